// Round 20
// baseline (776.632 us; speedup 1.0000x reference)
//
#include <hip/hip_runtime.h>
#include <hip/hip_fp16.h>
#include <math.h>

#define CCH 48
#define SDIM 32
#define SVOL (SDIM*SDIM*SDIM)
#define NB 2

typedef _Float16 half2_t __attribute__((ext_vector_type(2)));

static __device__ __forceinline__ float dot2f(half2_t a, half2_t b, float c) {
#if __has_builtin(__builtin_amdgcn_fdot2)
    return __builtin_amdgcn_fdot2(a, b, c, false);
#else
    return c + (float)a[0] * (float)b[0] + (float)a[1] * (float)b[1];
#endif
}

// ======== one-off weight reshape kernels ========

__global__ __launch_bounds__(256)
void reshape_pair_kernel(const float* __restrict__ w, half2_t* __restrict__ wt, int NO) {
    int i = blockIdx.x * 256 + threadIdx.x;
    int total = 27 * 24 * NO;
    if (i < total) {
        int o = i % NO; int rem = i / NO; int cp = rem % 24; int k = rem / 24;
        float w0 = w[((size_t)o * CCH + 2 * cp) * 27 + k];
        float w1 = w[((size_t)o * CCH + 2 * cp + 1) * 27 + k];
        wt[i] = half2_t{ (_Float16)w0, (_Float16)w1 };
    }
}

__global__ __launch_bounds__(256)
void t1x1_pair_kernel(const float* __restrict__ w, half2_t* __restrict__ wt) {
    int i = blockIdx.x * 256 + threadIdx.x;
    if (i < 24 * CCH) {
        int o = i % CCH, cp = i / CCH;
        wt[i] = half2_t{ (_Float16)w[o * CCH + 2 * cp], (_Float16)w[o * CCH + 2 * cp + 1] };
    }
}

__global__ __launch_bounds__(256)
void t1x1_kernel(const float* __restrict__ w, float* __restrict__ wt) {
    int i = blockIdx.x * 256 + threadIdx.x;
    if (i < CCH * CCH) { int ci = i / CCH, o = i % CCH; wt[i] = w[o * CCH + ci]; }
}

__global__ __launch_bounds__(64)
void cb_kernel(const float* __restrict__ c1w, const float* __restrict__ c1b,
               const float* __restrict__ dcb, float* __restrict__ cb) {
    int o = threadIdx.x;
    if (o < CCH) {
        float v = c1b[o];
        for (int ci = 0; ci < CCH; ci++) v += c1w[o * CCH + ci] * dcb[ci];
        cb[o] = v;
    }
}

// ---------------- LayerNorm over C; writes fp32 xn AND half2-pair xnp ----------------
__global__ __launch_bounds__(256)
void ln_kernel(const float* __restrict__ x, const float* __restrict__ ln_s,
               const float* __restrict__ ln_b, float* __restrict__ xn,
               half2_t* __restrict__ xnp) {
    int s = blockIdx.x * 256 + threadIdx.x;
    int b = blockIdx.y;
    const float* xb = x + (size_t)b * CCH * SVOL + s;
    float v[CCH];
    float mu = 0.f;
    #pragma unroll
    for (int c = 0; c < CCH; c++) { v[c] = xb[c * SVOL]; mu += v[c]; }
    mu *= (1.0f / CCH);
    float var = 0.f;
    #pragma unroll
    for (int c = 0; c < CCH; c++) { float d = v[c] - mu; var += d * d; }
    var *= (1.0f / CCH);
    float inv = rsqrtf(var + 1e-5f);
    float* o = xn + (size_t)b * CCH * SVOL + s;
    float nv[CCH];
    #pragma unroll
    for (int c = 0; c < CCH; c++) { nv[c] = (v[c] - mu) * inv * ln_s[c] + ln_b[c]; o[c * SVOL] = nv[c]; }
    half2_t* xp = xnp + (size_t)b * 24 * SVOL + s;
    #pragma unroll
    for (int cp = 0; cp < 24; cp++)
        xp[(size_t)cp * SVOL] = half2_t{ (_Float16)nv[2 * cp], (_Float16)nv[2 * cp + 1] };
}

// ---------------- 1x1x1 conv + exact GELU (4 groups x 12), fp16 dot2; half2-pair output ----
__global__ __launch_bounds__(256, 4)
void p1_gelu_kernel(const half2_t* __restrict__ xnp, const half2_t* __restrict__ wt,
                    const float* __restrict__ bias, half2_t* __restrict__ up) {
    int tid = threadIdx.x;
    int g = blockIdx.y, b = blockIdx.z;
    int s = blockIdx.x * 256 + tid;
    const half2_t* xb = xnp + (size_t)b * 24 * SVOL + s;
    float acc[12];
    #pragma unroll
    for (int o = 0; o < 12; o++) acc[o] = bias[g * 12 + o];
    for (int cp = 0; cp < 24; cp++) {
        half2_t v2 = xb[(size_t)cp * SVOL];
        const half2_t* wr = wt + cp * CCH + g * 12;
        #pragma unroll
        for (int o = 0; o < 12; o++) acc[o] = dot2f(v2, wr[o], acc[o]);
    }
    float gv[12];
    #pragma unroll
    for (int o = 0; o < 12; o++) {
        float a = acc[o];
        gv[o] = 0.5f * a * (1.0f + erff(a * 0.70710678118654752f));
    }
    half2_t* ub = up + ((size_t)b * 24 + g * 6) * SVOL + s;
    #pragma unroll
    for (int j = 0; j < 6; j++)
        ub[(size_t)j * SVOL] = half2_t{ (_Float16)gv[2 * j], (_Float16)gv[2 * j + 1] };
}

// ---- depthwise 5x5x5 pad 2: channel-pair half2, 8 z/thread, fp32 accum ----
__global__ __launch_bounds__(256, 4)
void dw5_kernel(const half2_t* __restrict__ in, const float* __restrict__ w,
                const float* __restrict__ bias, half2_t* __restrict__ out) {
    int tid = threadIdx.x;
    int cp = blockIdx.y, b = blockIdx.z;
    const float* wc0 = w + (2 * cp) * 125;        // uniform
    const float* wc1 = wc0 + 125;
    int bx = blockIdx.x;                          // 0..15
    int yx = (bx >> 2) * 256 + tid;               // 4 yx-chunks
    int z0 = (bx & 3) * 8;                        // 4 z-chunks of 8
    int y = yx >> 5, xx = yx & 31;
    const half2_t* ib = in + ((size_t)b * 24 + cp) * SVOL;
    float accA[8], accB[8];
    float bv0 = bias[2 * cp], bv1 = bias[2 * cp + 1];
    #pragma unroll
    for (int z = 0; z < 8; z++) { accA[z] = bv0; accB[z] = bv1; }
    for (int ty = 0; ty < 5; ty++) {
        int yy = y + ty - 2; if (yy < 0 || yy >= 32) continue;
        for (int tx = 0; tx < 5; tx++) {
            int xv = xx + tx - 2; if (xv < 0 || xv >= 32) continue;
            const half2_t* col = ib + yy * 32 + xv;
            float ca[12], cbv[12];                // window [z0-2, z0+9]
            #pragma unroll
            for (int j = 0; j < 12; j++) {
                int zz = z0 - 2 + j;
                if (zz >= 0 && zz < 32) {
                    half2_t v = col[(size_t)zz * 1024];
                    ca[j] = (float)v[0]; cbv[j] = (float)v[1];
                } else { ca[j] = 0.f; cbv[j] = 0.f; }
            }
            #pragma unroll
            for (int tz = 0; tz < 5; tz++) {
                float w0 = wc0[(tz * 5 + ty) * 5 + tx];
                float w1 = wc1[(tz * 5 + ty) * 5 + tx];
                #pragma unroll
                for (int z = 0; z < 8; z++) {
                    accA[z] += w0 * ca[z + tz];
                    accB[z] += w1 * cbv[z + tz];
                }
            }
        }
    }
    half2_t* ob = out + ((size_t)b * 24 + cp) * SVOL + y * 32 + xx;
    #pragma unroll
    for (int z = 0; z < 8; z++)
        ob[(size_t)(z0 + z) * 1024] = half2_t{ (_Float16)accA[z], (_Float16)accB[z] };
}

// ---- depthwise 7x7x7 dil 3 pad 9: channel-pair half2, 8 z/thread, fp32 accum ----
// Output IS a1p (half2 [24][S]) consumed by offconv + transpose.
__global__ __launch_bounds__(256, 4)
void dw7_kernel(const half2_t* __restrict__ in, const float* __restrict__ w,
                const float* __restrict__ bias, half2_t* __restrict__ out) {
    int tid = threadIdx.x;
    int cp = blockIdx.y, b = blockIdx.z;
    const float* wc0 = w + (2 * cp) * 343;        // uniform
    const float* wc1 = wc0 + 343;
    int bx = blockIdx.x;
    int yx = (bx >> 2) * 256 + tid;
    int z0 = (bx & 3) * 8;
    int y = yx >> 5, xx = yx & 31;
    const half2_t* ib = in + ((size_t)b * 24 + cp) * SVOL;
    float accA[8], accB[8];
    float bv0 = bias[2 * cp], bv1 = bias[2 * cp + 1];
    #pragma unroll
    for (int z = 0; z < 8; z++) { accA[z] = bv0; accB[z] = bv1; }
    for (int ty = 0; ty < 7; ty++) {
        int yy = y + 3 * (ty - 3); if (yy < 0 || yy >= 32) continue;
        for (int tx = 0; tx < 7; tx++) {
            int xv = xx + 3 * (tx - 3); if (xv < 0 || xv >= 32) continue;
            const half2_t* col = ib + yy * 32 + xv;
            float ca[26], cbv[26];                // window [z0-9, z0+16]
            #pragma unroll
            for (int j = 0; j < 26; j++) {
                int zz = z0 - 9 + j;
                if (zz >= 0 && zz < 32) {
                    half2_t v = col[(size_t)zz * 1024];
                    ca[j] = (float)v[0]; cbv[j] = (float)v[1];
                } else { ca[j] = 0.f; cbv[j] = 0.f; }
            }
            #pragma unroll
            for (int tz = 0; tz < 7; tz++) {
                float w0 = wc0[(tz * 7 + ty) * 7 + tx];
                float w1 = wc1[(tz * 7 + ty) * 7 + tx];
                #pragma unroll
                for (int z = 0; z < 8; z++) {
                    accA[z] += w0 * ca[z + 3 * tz];
                    accB[z] += w1 * cbv[z + 3 * tz];
                }
            }
        }
    }
    half2_t* ob = out + ((size_t)b * 24 + cp) * SVOL + y * 32 + xx;
    #pragma unroll
    for (int z = 0; z < 8; z++)
        ob[(size_t)(z0 + z) * 1024] = half2_t{ (_Float16)accA[z], (_Float16)accB[z] };
}

// ---- a1p (half2 [24][S]) -> a1h fp16 [S][48] (deform operand) ----
__global__ __launch_bounds__(256)
void transpose_pack_kernel(const half2_t* __restrict__ a1p, __half* __restrict__ a1h) {
    __shared__ float tile[CCH * 65];
    int tid = threadIdx.x;
    int b = blockIdx.y;
    int s0 = blockIdx.x * 64;
    for (int i = tid; i < 24 * 64; i += 256) {
        int cp = i >> 6, p = i & 63;
        half2_t v = a1p[((size_t)b * 24 + cp) * SVOL + s0 + p];
        tile[(2 * cp) * 65 + p] = (float)v[0];
        tile[(2 * cp + 1) * 65 + p] = (float)v[1];
    }
    __syncthreads();
    __half* ob = a1h + ((size_t)b * SVOL + s0) * CCH;
    for (int i = tid; i < 64 * CCH; i += 256) {
        int p = i / CCH, c = i % CCH;
        ob[i] = __float2half(tile[c * 65 + p]);
    }
}

// ---- offset conv 3x3x3: 48->81, pair-split 2 x out-split 3, fp16 dot2, atomic, NO bias ----
__global__ __launch_bounds__(256, 4)
void offconv_kernel(const half2_t* __restrict__ a1p, const half2_t* __restrict__ wt,
                    float* __restrict__ off) {
    int tid = threadIdx.x;
    int go = blockIdx.y % 3;
    int gc = blockIdx.y / 3;        // 0..1 (12 pairs each)
    int b = blockIdx.z;
    int s = blockIdx.x * 256 + tid;
    int z = s >> 10, y = (s >> 5) & 31, xx = s & 31;
    const half2_t* ib = a1p + ((size_t)b * 24 + gc * 12) * SVOL;
    float acc[27];
    #pragma unroll
    for (int o = 0; o < 27; o++) acc[o] = 0.f;
    for (int tap = 0; tap < 27; tap++) {
        int dz = tap / 9 - 1, dy = (tap / 3) % 3 - 1, dx = tap % 3 - 1;
        int zz = z + dz, yy = y + dy, xv = xx + dx;
        bool ok = (zz >= 0 && zz < 32 && yy >= 0 && yy < 32 && xv >= 0 && xv < 32);
        if (ok) {
            int si = (zz * 32 + yy) * 32 + xv;
            for (int cp = 0; cp < 12; cp++) {
                half2_t v2 = ib[(size_t)cp * SVOL + si];
                const half2_t* wr = wt + ((size_t)tap * 24 + gc * 12 + cp) * 81 + go * 27;  // uniform
                #pragma unroll
                for (int o = 0; o < 27; o++) acc[o] = dot2f(v2, wr[o], acc[o]);
            }
        }
    }
    float* obuf = off + (size_t)b * 81 * SVOL + (size_t)(go * 27) * SVOL + s;
    #pragma unroll
    for (int o = 0; o < 27; o++) atomicAdd(&obuf[(size_t)o * SVOL], acc[o]);
}

// ---- deformable conv 3x3x3: ci-split 3 (16 ch), packed fp16 interp + dot2 matmul ----
struct h8v { half2_t a, b, c, d; };   // 16 bytes = 8 halves

__global__ __launch_bounds__(256, 4)
void deform_kernel(const __half* __restrict__ a1h, const float* __restrict__ off,
                   const float* __restrict__ off_b,
                   const half2_t* __restrict__ wt, float* __restrict__ out) {
    int tid = threadIdx.x;
    int gc = blockIdx.y;            // ci group 0..2 (16 ch = 8 pairs each)
    int b = blockIdx.z;
    int s = blockIdx.x * 256 + tid;
    int z = s >> 10, y = (s >> 5) & 31, xx = s & 31;
    const __half* abase = a1h + (size_t)b * SVOL * CCH + gc * 16;
    const float* ob = off + (size_t)b * 81 * SVOL + s;
    float acc[CCH];
    #pragma unroll
    for (int o = 0; o < CCH; o++) acc[o] = 0.f;
    for (int k = 0; k < 27; k++) {
        int kd = k / 9 - 1, kh = (k / 3) % 3 - 1, kw = k % 3 - 1;
        float zf = (float)(z + kd) + ob[(size_t)(k * 3 + 0) * SVOL] + off_b[k * 3 + 0];
        float yf = (float)(y + kh) + ob[(size_t)(k * 3 + 1) * SVOL] + off_b[k * 3 + 1];
        float xf = (float)(xx + kw) + ob[(size_t)(k * 3 + 2) * SVOL] + off_b[k * 3 + 2];
        float z0 = floorf(zf), y0 = floorf(yf), x0 = floorf(xf);
        float tz = zf - z0, ty = yf - y0, tx = xf - x0;
        int iz0 = (int)z0, iy0 = (int)y0, ix0 = (int)x0;
        half2_t val2[8];
        #pragma unroll
        for (int j = 0; j < 8; j++) val2[j] = (half2_t)(_Float16)0;
        #pragma unroll
        for (int corner = 0; corner < 8; corner++) {
            int dz = corner >> 2, dy = (corner >> 1) & 1, dx = corner & 1;
            int zi = iz0 + dz, yi = iy0 + dy, xi = ix0 + dx;
            bool valid = (zi >= 0 && zi < 32 && yi >= 0 && yi < 32 && xi >= 0 && xi < 32);
            float wgt = (dz ? tz : 1.f - tz) * (dy ? ty : 1.f - ty) * (dx ? tx : 1.f - tx);
            float cwv = valid ? wgt : 0.f;
            _Float16 cwh = (_Float16)cwv;
            half2_t cw2 = { cwh, cwh };
            int zc = min(max(zi, 0), 31), yc = min(max(yi, 0), 31), xc = min(max(xi, 0), 31);
            int cidx = (zc * 32 + yc) * 32 + xc;
            const h8v* pv = (const h8v*)(abase + (size_t)cidx * CCH);
            h8v q0 = pv[0], q1 = pv[1];
            val2[0] += cw2 * q0.a;  val2[1] += cw2 * q0.b;
            val2[2] += cw2 * q0.c;  val2[3] += cw2 * q0.d;
            val2[4] += cw2 * q1.a;  val2[5] += cw2 * q1.b;
            val2[6] += cw2 * q1.c;  val2[7] += cw2 * q1.d;
        }
        #pragma unroll
        for (int cpl = 0; cpl < 8; cpl++) {
            half2_t v2 = val2[cpl];
            const half2_t* wr = wt + ((size_t)k * 24 + gc * 8 + cpl) * CCH;  // uniform
            #pragma unroll
            for (int o = 0; o < CCH; o++) acc[o] = dot2f(v2, wr[o], acc[o]);
        }
    }
    float* op = out + (size_t)b * CCH * SVOL + s;
    #pragma unroll
    for (int o = 0; o < CCH; o++) atomicAdd(&op[(size_t)o * SVOL], acc[o]);
}

// ---- gate1: a2 = (c1 . dc + cb) * u (fp16 u); writes half2-pair a2p ----
__global__ __launch_bounds__(256, 4)
void gate1_kernel(const float* __restrict__ dc, const half2_t* __restrict__ up,
                  const float* __restrict__ wt, const float* __restrict__ cb,
                  half2_t* __restrict__ a2p) {
    int tid = threadIdx.x;
    int g = blockIdx.y, b = blockIdx.z;
    int s = blockIdx.x * 256 + tid;
    size_t base = (size_t)b * CCH * SVOL + s;
    float acc[12];
    #pragma unroll
    for (int o = 0; o < 12; o++) acc[o] = cb[g * 12 + o];
    for (int ci = 0; ci < CCH; ci++) {
        float v = dc[base + (size_t)ci * SVOL];
        const float* wr = wt + ci * CCH + g * 12;
        #pragma unroll
        for (int o = 0; o < 12; o++) acc[o] += wr[o] * v;
    }
    const half2_t* ub = up + ((size_t)b * 24 + g * 6) * SVOL + s;
    #pragma unroll
    for (int j = 0; j < 6; j++) {
        half2_t uv = ub[(size_t)j * SVOL];
        acc[2 * j]     *= (float)uv[0];
        acc[2 * j + 1] *= (float)uv[1];
    }
    half2_t* ap = a2p + ((size_t)b * 24 + g * 6) * SVOL + s;
    #pragma unroll
    for (int j = 0; j < 6; j++)
        ap[(size_t)j * SVOL] = half2_t{ (_Float16)acc[2 * j], (_Float16)acc[2 * j + 1] };
}

// ---- gate2: skip = x + gamma*(p2 . a2 + p2b + xn), fp16 dot2; writes fp32 skip + half2 skp ----
__global__ __launch_bounds__(256, 4)
void gate2_kernel(const half2_t* __restrict__ a2p, const float* __restrict__ xn,
                  const float* __restrict__ x,
                  const half2_t* __restrict__ wt, const float* __restrict__ p2b,
                  const float* __restrict__ gamma, float* __restrict__ skip,
                  half2_t* __restrict__ skp) {
    int tid = threadIdx.x;
    int g = blockIdx.y, b = blockIdx.z;
    int s = blockIdx.x * 256 + tid;
    size_t base = (size_t)b * CCH * SVOL + s;
    const half2_t* ab = a2p + (size_t)b * 24 * SVOL + s;
    float acc[12];
    #pragma unroll
    for (int o = 0; o < 12; o++) acc[o] = p2b[g * 12 + o];
    for (int cp = 0; cp < 24; cp++) {
        half2_t v2 = ab[(size_t)cp * SVOL];
        const half2_t* wr = wt + cp * CCH + g * 12;
        #pragma unroll
        for (int o = 0; o < 12; o++) acc[o] = dot2f(v2, wr[o], acc[o]);
    }
    float sv[12];
    #pragma unroll
    for (int o = 0; o < 12; o++) {
        int oc = g * 12 + o;
        float vv = acc[o] + xn[base + (size_t)oc * SVOL];
        sv[o] = x[base + (size_t)oc * SVOL] + gamma[oc] * vv;
        skip[base + (size_t)oc * SVOL] = sv[o];
    }
    half2_t* sp = skp + ((size_t)b * 24 + g * 6) * SVOL + s;
    #pragma unroll
    for (int j = 0; j < 6; j++)
        sp[(size_t)j * SVOL] = half2_t{ (_Float16)sv[2 * j], (_Float16)sv[2 * j + 1] };
}

// ---- u1: 3x3x3 conv + BN1 + LeakyReLU, fp16 dot2; writes packed half2 output ----
__global__ __launch_bounds__(256, 4)
void u1_kernel(const half2_t* __restrict__ skp, const half2_t* __restrict__ wt,
               const float* __restrict__ bs, const float* __restrict__ bb,
               const float* __restrict__ bm, const float* __restrict__ bv,
               half2_t* __restrict__ h1p) {
    int tid = threadIdx.x;
    int g = blockIdx.y, b = blockIdx.z;
    int s = blockIdx.x * 256 + tid;
    int z = s >> 10, y = (s >> 5) & 31, xx = s & 31;
    const half2_t* ib = skp + (size_t)b * 24 * SVOL;
    float acc[12];
    #pragma unroll
    for (int o = 0; o < 12; o++) acc[o] = 0.f;
    for (int tap = 0; tap < 27; tap++) {
        int dz = tap / 9 - 1, dy = (tap / 3) % 3 - 1, dx = tap % 3 - 1;
        int zz = z + dz, yy = y + dy, xv = xx + dx;
        bool ok = (zz >= 0 && zz < 32 && yy >= 0 && yy < 32 && xv >= 0 && xv < 32);
        if (ok) {
            int si = (zz * 32 + yy) * 32 + xv;
            for (int cp = 0; cp < 24; cp++) {
                half2_t v2 = ib[(size_t)cp * SVOL + si];
                const half2_t* wr = wt + ((size_t)tap * 24 + cp) * CCH + g * 12;  // uniform
                #pragma unroll
                for (int o = 0; o < 12; o++) acc[o] = dot2f(v2, wr[o], acc[o]);
            }
        }
    }
    float hv[12];
    #pragma unroll
    for (int o = 0; o < 12; o++) {
        int oc = g * 12 + o;
        float inv = rsqrtf(bv[oc] + 1e-5f);
        float h = (acc[o] - bm[oc]) * (bs[oc] * inv) + bb[oc];
        hv[o] = h >= 0.f ? h : 0.01f * h;
    }
    half2_t* op = h1p + ((size_t)b * 24 + g * 6) * SVOL + s;
    #pragma unroll
    for (int j = 0; j < 6; j++)
        op[(size_t)j * SVOL] = half2_t{ (_Float16)hv[2 * j], (_Float16)hv[2 * j + 1] };
}

// ---- u2_bn: 3x3x3 conv (fp16 dot2) + BN2 + (+skip fp32) + LeakyReLU -> attnp half2 ----
__global__ __launch_bounds__(256, 4)
void u2_bn_kernel(const half2_t* __restrict__ h1p, const float* __restrict__ skip,
                  const half2_t* __restrict__ wt,
                  const float* __restrict__ bs, const float* __restrict__ bb,
                  const float* __restrict__ bm, const float* __restrict__ bv,
                  half2_t* __restrict__ attnp) {
    int tid = threadIdx.x;
    int g = blockIdx.y, b = blockIdx.z;
    int s = blockIdx.x * 256 + tid;
    int z = s >> 10, y = (s >> 5) & 31, xx = s & 31;
    const half2_t* ib = h1p + (size_t)b * 24 * SVOL;
    float acc[12];
    #pragma unroll
    for (int o = 0; o < 12; o++) acc[o] = 0.f;
    for (int tap = 0; tap < 27; tap++) {
        int dz = tap / 9 - 1, dy = (tap / 3) % 3 - 1, dx = tap % 3 - 1;
        int zz = z + dz, yy = y + dy, xv = xx + dx;
        bool ok = (zz >= 0 && zz < 32 && yy >= 0 && yy < 32 && xv >= 0 && xv < 32);
        if (ok) {
            int si = (zz * 32 + yy) * 32 + xv;
            for (int cp = 0; cp < 24; cp++) {
                half2_t v2 = ib[(size_t)cp * SVOL + si];
                const half2_t* wr = wt + ((size_t)tap * 24 + cp) * CCH + g * 12;  // uniform
                #pragma unroll
                for (int o = 0; o < 12; o++) acc[o] = dot2f(v2, wr[o], acc[o]);
            }
        }
    }
    size_t base = (size_t)b * CCH * SVOL + s;
    float av[12];
    #pragma unroll
    for (int o = 0; o < 12; o++) {
        int oc = g * 12 + o;
        float inv = rsqrtf(bv[oc] + 1e-5f);
        float h = (acc[o] - bm[oc]) * (bs[oc] * inv) + bb[oc];
        float a = h + skip[base + (size_t)oc * SVOL];
        av[o] = a >= 0.f ? a : 0.01f * a;
    }
    half2_t* op = attnp + ((size_t)b * 24 + g * 6) * SVOL + s;
    #pragma unroll
    for (int j = 0; j < 6; j++)
        op[(size_t)j * SVOL] = half2_t{ (_Float16)av[2 * j], (_Float16)av[2 * j + 1] };
}

// ---- pr_final: out = skip + pr(attn), fp16 dot2 ----
__global__ __launch_bounds__(256, 4)
void pr_final_kernel(const half2_t* __restrict__ attnp, const float* __restrict__ skip,
                     const half2_t* __restrict__ wt, const float* __restrict__ prb,
                     float* __restrict__ out) {
    int tid = threadIdx.x;
    int g = blockIdx.y, b = blockIdx.z;
    int s = blockIdx.x * 256 + tid;
    size_t base = (size_t)b * CCH * SVOL + s;
    const half2_t* ab = attnp + (size_t)b * 24 * SVOL + s;
    float acc[12];
    #pragma unroll
    for (int o = 0; o < 12; o++) acc[o] = prb[g * 12 + o];
    for (int cp = 0; cp < 24; cp++) {
        half2_t v2 = ab[(size_t)cp * SVOL];
        const half2_t* wr = wt + cp * CCH + g * 12;
        #pragma unroll
        for (int o = 0; o < 12; o++) acc[o] = dot2f(v2, wr[o], acc[o]);
    }
    #pragma unroll
    for (int o = 0; o < 12; o++) {
        int oc = g * 12 + o;
        out[base + (size_t)oc * SVOL] = skip[base + (size_t)oc * SVOL] + acc[o];
    }
}

extern "C" void kernel_launch(void* const* d_in, const int* in_sizes, int n_in,
                              void* d_out, int out_size, void* d_ws, size_t ws_size,
                              hipStream_t stream) {
    (void)in_sizes; (void)n_in; (void)out_size; (void)ws_size;
    const float* x     = (const float*)d_in[0];
    const float* ln_s  = (const float*)d_in[1];
    const float* ln_b  = (const float*)d_in[2];
    const float* gamma = (const float*)d_in[3];
    const float* p1_w  = (const float*)d_in[4];
    const float* p1_b  = (const float*)d_in[5];
    const float* p2_w  = (const float*)d_in[6];
    const float* p2_b  = (const float*)d_in[7];
    const float* c0_w  = (const float*)d_in[8];
    const float* c0_b  = (const float*)d_in[9];
    const float* cs_w  = (const float*)d_in[10];
    const float* cs_b  = (const float*)d_in[11];
    const float* off_w = (const float*)d_in[12];
    const float* off_b = (const float*)d_in[13];
    const float* dc_w  = (const float*)d_in[14];
    const float* dc_b  = (const float*)d_in[15];
    const float* c1_w  = (const float*)d_in[16];
    const float* c1_b  = (const float*)d_in[17];
    const float* u1_w  = (const float*)d_in[18];
    const float* bn1_s = (const float*)d_in[19];
    const float* bn1_b = (const float*)d_in[20];
    const float* bn1_m = (const float*)d_in[21];
    const float* bn1_v = (const float*)d_in[22];
    const float* u2_w  = (const float*)d_in[23];
    const float* bn2_s = (const float*)d_in[24];
    const float* bn2_b = (const float*)d_in[25];
    const float* bn2_m = (const float*)d_in[26];
    const float* bn2_v = (const float*)d_in[27];
    const float* pr_w  = (const float*)d_in[28];
    const float* pr_b  = (const float*)d_in[29];
    float* out = (float*)d_out;

    float* wsf = (float*)d_ws;
    const size_t TS = (size_t)NB * CCH * SVOL;   // 3,145,728 floats
    float* xn   = out;            // d_out doubles as xn fp32 (dead after gate2)
    float* ubuf = wsf;            // up (half2) -> [skp | h1p] (half2)
    float* bufA = wsf + TS;       // [dw5p | a1p] (half2) -> a1h -> skip (fp32)
    float* bufB = wsf + 2 * TS;   // xnp (half2) -> deform partials (dc)
    float* offb = wsf + 3 * TS;   // offset partials [B,81,S] -> a2p (half2) -> attnp (half2)
    float* wtb    = wsf + 3 * TS + (size_t)NB * 81 * SVOL;
    float* wt_offf = wtb;
    float* wt_dcf  = wt_offf + 104976;
    float* wt_u1f  = wt_dcf + 62208;
    float* wt_u2f  = wt_u1f + 62208;
    float* pt_p1  = wt_u2f + 62208;
    float* pt_c1  = pt_p1 + 2304;
    float* pt_p2  = pt_c1 + 2304;
    float* pt_pr  = pt_p2 + 2304;
    float* cb_all = pt_pr + 2304;

    half2_t* up   = (half2_t*)ubuf;                     // dead after gate1
    half2_t* skp  = (half2_t*)ubuf;                     // written by gate2 (up dead)
    half2_t* h1p  = (half2_t*)(ubuf + TS / 2);
    half2_t* dw5p = (half2_t*)bufA;                     // dead after dw7
    half2_t* a1p  = (half2_t*)(bufA + TS / 2);          // dw7 out; offconv+transpose input
    __half*  a1h  = (__half*)bufA;                      // written after dw5p dead
    half2_t* xnp  = (half2_t*)bufB;                     // dead after p1
    half2_t* a2p  = (half2_t*)offb;                     // offsets dead after deform
    half2_t* attnp = (half2_t*)offb;                    // a2p dead after gate2
    half2_t* wt_offh = (half2_t*)wt_offf;
    half2_t* wt_dch  = (half2_t*)wt_dcf;
    half2_t* wt_u1h  = (half2_t*)wt_u1f;
    half2_t* wt_u2h  = (half2_t*)wt_u2f;
    half2_t* wt_p1h  = (half2_t*)pt_p1;
    half2_t* wt_p2h  = (half2_t*)pt_p2;
    half2_t* wt_prh  = (half2_t*)pt_pr;

    dim3 blk(256);
    dim3 gpos(SVOL / 256, NB);
    dim3 g4(SVOL / 256, 4, NB);
    dim3 g6(SVOL / 256, 6, NB);        // offconv: pair-split 2 x out-split 3
    dim3 g3d(SVOL / 256, 3, NB);
    dim3 gdwc(16, 24, NB);             // channel-pair depthwise: 16 x 24 x 2 = 768 blocks
    dim3 gtr(SVOL / 64, NB);

    hipLaunchKernelGGL(reshape_pair_kernel, dim3((27 * 24 * 81 + 255) / 256), blk, 0, stream, off_w, wt_offh, 81);
    hipLaunchKernelGGL(reshape_pair_kernel, dim3((27 * 24 * 48 + 255) / 256), blk, 0, stream, dc_w,  wt_dch,  48);
    hipLaunchKernelGGL(reshape_pair_kernel, dim3((27 * 24 * 48 + 255) / 256), blk, 0, stream, u1_w,  wt_u1h,  48);
    hipLaunchKernelGGL(reshape_pair_kernel, dim3((27 * 24 * 48 + 255) / 256), blk, 0, stream, u2_w,  wt_u2h,  48);
    hipLaunchKernelGGL(t1x1_pair_kernel, dim3(5), blk, 0, stream, p1_w, wt_p1h);
    hipLaunchKernelGGL(t1x1_pair_kernel, dim3(5), blk, 0, stream, p2_w, wt_p2h);
    hipLaunchKernelGGL(t1x1_pair_kernel, dim3(5), blk, 0, stream, pr_w, wt_prh);
    hipLaunchKernelGGL(t1x1_kernel, dim3(9), blk, 0, stream, c1_w, pt_c1);
    hipLaunchKernelGGL(cb_kernel, dim3(1), dim3(64), 0, stream, c1_w, c1_b, dc_b, cb_all);

    hipLaunchKernelGGL(ln_kernel,            gpos, blk, 0, stream, x, ln_s, ln_b, xn, xnp);
    hipLaunchKernelGGL(p1_gelu_kernel,       g4,   blk, 0, stream, xnp, wt_p1h, p1_b, up);
    hipLaunchKernelGGL(dw5_kernel,           gdwc, blk, 0, stream, up, c0_w, c0_b, dw5p);
    hipLaunchKernelGGL(dw7_kernel,           gdwc, blk, 0, stream, dw5p, cs_w, cs_b, a1p);
    hipLaunchKernelGGL(transpose_pack_kernel, gtr, blk, 0, stream, a1p, a1h);
    hipMemsetAsync(offb, 0, (size_t)NB * 81 * SVOL * sizeof(float), stream);
    hipLaunchKernelGGL(offconv_kernel,       g6,   blk, 0, stream, a1p, wt_offh, offb);
    hipMemsetAsync(bufB, 0, TS * sizeof(float), stream);
    hipLaunchKernelGGL(deform_kernel,        g3d,  blk, 0, stream, a1h, offb, off_b, wt_dch, bufB);
    hipLaunchKernelGGL(gate1_kernel,         g4,   blk, 0, stream, bufB, up, pt_c1, cb_all, a2p);
    hipLaunchKernelGGL(gate2_kernel,         g4,   blk, 0, stream, a2p, xn, x, wt_p2h, p2_b, gamma,
                       bufA, skp);
    hipLaunchKernelGGL(u1_kernel,            g4,   blk, 0, stream, skp, wt_u1h,
                       bn1_s, bn1_b, bn1_m, bn1_v, h1p);
    hipLaunchKernelGGL(u2_bn_kernel,         g4,   blk, 0, stream, h1p, bufA, wt_u2h,
                       bn2_s, bn2_b, bn2_m, bn2_v, attnp);
    hipLaunchKernelGGL(pr_final_kernel,      g4,   blk, 0, stream, attnp, bufA, wt_prh, pr_b, out);
}

// Round 21
// 662.734 us; speedup vs baseline: 1.1719x; 1.1719x over previous
//
#include <hip/hip_runtime.h>
#include <hip/hip_fp16.h>
#include <math.h>

#define CCH 48
#define SDIM 32
#define SVOL (SDIM*SDIM*SDIM)
#define NB 2

typedef _Float16 half2_t __attribute__((ext_vector_type(2)));

static __device__ __forceinline__ float dot2f(half2_t a, half2_t b, float c) {
#if __has_builtin(__builtin_amdgcn_fdot2)
    return __builtin_amdgcn_fdot2(a, b, c, false);
#else
    return c + (float)a[0] * (float)b[0] + (float)a[1] * (float)b[1];
#endif
}

// ======== one-off weight reshape kernels ========

__global__ __launch_bounds__(256)
void reshape_pair_kernel(const float* __restrict__ w, half2_t* __restrict__ wt, int NO) {
    int i = blockIdx.x * 256 + threadIdx.x;
    int total = 27 * 24 * NO;
    if (i < total) {
        int o = i % NO; int rem = i / NO; int cp = rem % 24; int k = rem / 24;
        float w0 = w[((size_t)o * CCH + 2 * cp) * 27 + k];
        float w1 = w[((size_t)o * CCH + 2 * cp + 1) * 27 + k];
        wt[i] = half2_t{ (_Float16)w0, (_Float16)w1 };
    }
}

__global__ __launch_bounds__(256)
void t1x1_pair_kernel(const float* __restrict__ w, half2_t* __restrict__ wt) {
    int i = blockIdx.x * 256 + threadIdx.x;
    if (i < 24 * CCH) {
        int o = i % CCH, cp = i / CCH;
        wt[i] = half2_t{ (_Float16)w[o * CCH + 2 * cp], (_Float16)w[o * CCH + 2 * cp + 1] };
    }
}

__global__ __launch_bounds__(256)
void t1x1_kernel(const float* __restrict__ w, float* __restrict__ wt) {
    int i = blockIdx.x * 256 + threadIdx.x;
    if (i < CCH * CCH) { int ci = i / CCH, o = i % CCH; wt[i] = w[o * CCH + ci]; }
}

__global__ __launch_bounds__(64)
void cb_kernel(const float* __restrict__ c1w, const float* __restrict__ c1b,
               const float* __restrict__ dcb, float* __restrict__ cb) {
    int o = threadIdx.x;
    if (o < CCH) {
        float v = c1b[o];
        for (int ci = 0; ci < CCH; ci++) v += c1w[o * CCH + ci] * dcb[ci];
        cb[o] = v;
    }
}

// ---------------- LayerNorm over C; writes fp32 xn AND half2-pair xnp ----------------
__global__ __launch_bounds__(256)
void ln_kernel(const float* __restrict__ x, const float* __restrict__ ln_s,
               const float* __restrict__ ln_b, float* __restrict__ xn,
               half2_t* __restrict__ xnp) {
    int s = blockIdx.x * 256 + threadIdx.x;
    int b = blockIdx.y;
    const float* xb = x + (size_t)b * CCH * SVOL + s;
    float v[CCH];
    float mu = 0.f;
    #pragma unroll
    for (int c = 0; c < CCH; c++) { v[c] = xb[c * SVOL]; mu += v[c]; }
    mu *= (1.0f / CCH);
    float var = 0.f;
    #pragma unroll
    for (int c = 0; c < CCH; c++) { float d = v[c] - mu; var += d * d; }
    var *= (1.0f / CCH);
    float inv = rsqrtf(var + 1e-5f);
    float* o = xn + (size_t)b * CCH * SVOL + s;
    float nv[CCH];
    #pragma unroll
    for (int c = 0; c < CCH; c++) { nv[c] = (v[c] - mu) * inv * ln_s[c] + ln_b[c]; o[c * SVOL] = nv[c]; }
    half2_t* xp = xnp + (size_t)b * 24 * SVOL + s;
    #pragma unroll
    for (int cp = 0; cp < 24; cp++)
        xp[(size_t)cp * SVOL] = half2_t{ (_Float16)nv[2 * cp], (_Float16)nv[2 * cp + 1] };
}

// ---------------- 1x1x1 conv + exact GELU (4 groups x 12), fp16 dot2 ----------------
__global__ __launch_bounds__(256, 4)
void p1_gelu_kernel(const half2_t* __restrict__ xnp, const half2_t* __restrict__ wt,
                    const float* __restrict__ bias, float* __restrict__ u) {
    int tid = threadIdx.x;
    int g = blockIdx.y, b = blockIdx.z;
    int s = blockIdx.x * 256 + tid;
    const half2_t* xb = xnp + (size_t)b * 24 * SVOL + s;
    float acc[12];
    #pragma unroll
    for (int o = 0; o < 12; o++) acc[o] = bias[g * 12 + o];
    for (int cp = 0; cp < 24; cp++) {
        half2_t v2 = xb[(size_t)cp * SVOL];
        const half2_t* wr = wt + cp * CCH + g * 12;
        #pragma unroll
        for (int o = 0; o < 12; o++) acc[o] = dot2f(v2, wr[o], acc[o]);
    }
    float* ub = u + (size_t)b * CCH * SVOL + s + (size_t)(g * 12) * SVOL;
    #pragma unroll
    for (int o = 0; o < 12; o++) {
        float a = acc[o];
        ub[o * SVOL] = 0.5f * a * (1.0f + erff(a * 0.70710678118654752f));
    }
}

// ---- depthwise 5x5x5 pad 2: half-column blocking (16 z/thread, window cache) ----
__global__ __launch_bounds__(256, 4)
void dw5_kernel(const float* __restrict__ in, const float* __restrict__ w,
                const float* __restrict__ bias, float* __restrict__ out) {
    int tid = threadIdx.x;
    int c = blockIdx.y, b = blockIdx.z;
    const float* wc = w + c * 125;
    int bx = blockIdx.x;
    int yx = (bx >> 1) * 256 + tid;
    int z0 = (bx & 1) * 16;
    int y = yx >> 5, xx = yx & 31;
    const float* ib = in + ((size_t)b * CCH + c) * SVOL;
    float acc[16];
    float bv = bias[c];
    #pragma unroll
    for (int z = 0; z < 16; z++) acc[z] = bv;
    for (int ty = 0; ty < 5; ty++) {
        int yy = y + ty - 2; if (yy < 0 || yy >= 32) continue;
        for (int tx = 0; tx < 5; tx++) {
            int xv = xx + tx - 2; if (xv < 0 || xv >= 32) continue;
            const float* col = ib + yy * 32 + xv;
            float cv[20];
            #pragma unroll
            for (int j = 0; j < 20; j++) {
                int zz = z0 - 2 + j;
                cv[j] = (zz >= 0 && zz < 32) ? col[(size_t)zz * 1024] : 0.f;
            }
            #pragma unroll
            for (int tz = 0; tz < 5; tz++) {
                float wv = wc[(tz * 5 + ty) * 5 + tx];
                #pragma unroll
                for (int z = 0; z < 16; z++) acc[z] += wv * cv[z + tz];
            }
        }
    }
    float* ob = out + ((size_t)b * CCH + c) * SVOL + y * 32 + xx;
    #pragma unroll
    for (int z = 0; z < 16; z++) ob[(size_t)(z0 + z) * 1024] = acc[z];
}

// ---- depthwise 7x7x7 dil 3 pad 9: half-column blocking (16 z/thread, window cache) ----
__global__ __launch_bounds__(256, 4)
void dw7_kernel(const float* __restrict__ in, const float* __restrict__ w,
                const float* __restrict__ bias, float* __restrict__ out) {
    int tid = threadIdx.x;
    int c = blockIdx.y, b = blockIdx.z;
    const float* wc = w + c * 343;
    int bx = blockIdx.x;
    int yx = (bx >> 1) * 256 + tid;
    int z0 = (bx & 1) * 16;
    int y = yx >> 5, xx = yx & 31;
    const float* ib = in + ((size_t)b * CCH + c) * SVOL;
    float acc[16];
    float bv = bias[c];
    #pragma unroll
    for (int z = 0; z < 16; z++) acc[z] = bv;
    for (int ty = 0; ty < 7; ty++) {
        int yy = y + 3 * (ty - 3); if (yy < 0 || yy >= 32) continue;
        for (int tx = 0; tx < 7; tx++) {
            int xv = xx + 3 * (tx - 3); if (xv < 0 || xv >= 32) continue;
            const float* col = ib + yy * 32 + xv;
            float cv[34];
            #pragma unroll
            for (int j = 0; j < 34; j++) {
                int zz = z0 - 9 + j;
                cv[j] = (zz >= 0 && zz < 32) ? col[(size_t)zz * 1024] : 0.f;
            }
            #pragma unroll
            for (int tz = 0; tz < 7; tz++) {
                float wv = wc[(tz * 7 + ty) * 7 + tx];
                #pragma unroll
                for (int z = 0; z < 16; z++) acc[z] += wv * cv[z + 3 * tz];
            }
        }
    }
    float* ob = out + ((size_t)b * CCH + c) * SVOL + y * 32 + xx;
    #pragma unroll
    for (int z = 0; z < 16; z++) ob[(size_t)(z0 + z) * 1024] = acc[z];
}

// ---- fused: a1 fp32 [48][S] -> a1h fp16 [S][48] (deform) AND a1p half2 [24][S] (offconv) ----
__global__ __launch_bounds__(256)
void transpose_pack_kernel(const float* __restrict__ a1, __half* __restrict__ a1h,
                           half2_t* __restrict__ a1p) {
    __shared__ float tile[CCH * 65];
    int tid = threadIdx.x;
    int b = blockIdx.y;
    int s0 = blockIdx.x * 64;
    const float* ib = a1 + (size_t)b * CCH * SVOL + s0;
    for (int i = tid; i < CCH * 64; i += 256) {
        int c = i >> 6, p = i & 63;
        tile[c * 65 + p] = ib[(size_t)c * SVOL + p];
    }
    __syncthreads();
    __half* ob = a1h + ((size_t)b * SVOL + s0) * CCH;
    for (int i = tid; i < 64 * CCH; i += 256) {
        int p = i / CCH, c = i % CCH;
        ob[i] = __float2half(tile[c * 65 + p]);
    }
    for (int i = tid; i < 24 * 64; i += 256) {
        int cp = i >> 6, p = i & 63;
        a1p[((size_t)b * 24 + cp) * SVOL + s0 + p] =
            half2_t{ (_Float16)tile[(2 * cp) * 65 + p], (_Float16)tile[(2 * cp + 1) * 65 + p] };
    }
}

// ---- offset conv 3x3x3: 48->81, pair-split 2 x out-split 3, fp16 dot2, atomic, NO bias ----
__global__ __launch_bounds__(256, 4)
void offconv_kernel(const half2_t* __restrict__ a1p, const half2_t* __restrict__ wt,
                    float* __restrict__ off) {
    int tid = threadIdx.x;
    int go = blockIdx.y % 3;
    int gc = blockIdx.y / 3;        // 0..1 (12 pairs each)
    int b = blockIdx.z;
    int s = blockIdx.x * 256 + tid;
    int z = s >> 10, y = (s >> 5) & 31, xx = s & 31;
    const half2_t* ib = a1p + ((size_t)b * 24 + gc * 12) * SVOL;
    float acc[27];
    #pragma unroll
    for (int o = 0; o < 27; o++) acc[o] = 0.f;
    for (int tap = 0; tap < 27; tap++) {
        int dz = tap / 9 - 1, dy = (tap / 3) % 3 - 1, dx = tap % 3 - 1;
        int zz = z + dz, yy = y + dy, xv = xx + dx;
        bool ok = (zz >= 0 && zz < 32 && yy >= 0 && yy < 32 && xv >= 0 && xv < 32);
        if (ok) {
            int si = (zz * 32 + yy) * 32 + xv;
            for (int cp = 0; cp < 12; cp++) {
                half2_t v2 = ib[(size_t)cp * SVOL + si];
                const half2_t* wr = wt + ((size_t)tap * 24 + gc * 12 + cp) * 81 + go * 27;  // uniform
                #pragma unroll
                for (int o = 0; o < 27; o++) acc[o] = dot2f(v2, wr[o], acc[o]);
            }
        }
    }
    float* obuf = off + (size_t)b * 81 * SVOL + (size_t)(go * 27) * SVOL + s;
    #pragma unroll
    for (int o = 0; o < 27; o++) atomicAdd(&obuf[(size_t)o * SVOL], acc[o]);
}

// ---- deformable conv 3x3x3: ci-split 3 (16 ch), packed fp16 interp + dot2 matmul ----
struct h8v { half2_t a, b, c, d; };   // 16 bytes = 8 halves

__global__ __launch_bounds__(256, 4)
void deform_kernel(const __half* __restrict__ a1h, const float* __restrict__ off,
                   const float* __restrict__ off_b,
                   const half2_t* __restrict__ wt, float* __restrict__ out) {
    int tid = threadIdx.x;
    int gc = blockIdx.y;            // ci group 0..2 (16 ch = 8 pairs each)
    int b = blockIdx.z;
    int s = blockIdx.x * 256 + tid;
    int z = s >> 10, y = (s >> 5) & 31, xx = s & 31;
    const __half* abase = a1h + (size_t)b * SVOL * CCH + gc * 16;
    const float* ob = off + (size_t)b * 81 * SVOL + s;
    float acc[CCH];
    #pragma unroll
    for (int o = 0; o < CCH; o++) acc[o] = 0.f;
    for (int k = 0; k < 27; k++) {
        int kd = k / 9 - 1, kh = (k / 3) % 3 - 1, kw = k % 3 - 1;
        float zf = (float)(z + kd) + ob[(size_t)(k * 3 + 0) * SVOL] + off_b[k * 3 + 0];
        float yf = (float)(y + kh) + ob[(size_t)(k * 3 + 1) * SVOL] + off_b[k * 3 + 1];
        float xf = (float)(xx + kw) + ob[(size_t)(k * 3 + 2) * SVOL] + off_b[k * 3 + 2];
        float z0 = floorf(zf), y0 = floorf(yf), x0 = floorf(xf);
        float tz = zf - z0, ty = yf - y0, tx = xf - x0;
        int iz0 = (int)z0, iy0 = (int)y0, ix0 = (int)x0;
        half2_t val2[8];
        #pragma unroll
        for (int j = 0; j < 8; j++) val2[j] = (half2_t)(_Float16)0;
        #pragma unroll
        for (int corner = 0; corner < 8; corner++) {
            int dz = corner >> 2, dy = (corner >> 1) & 1, dx = corner & 1;
            int zi = iz0 + dz, yi = iy0 + dy, xi = ix0 + dx;
            bool valid = (zi >= 0 && zi < 32 && yi >= 0 && yi < 32 && xi >= 0 && xi < 32);
            float wgt = (dz ? tz : 1.f - tz) * (dy ? ty : 1.f - ty) * (dx ? tx : 1.f - tx);
            float cwv = valid ? wgt : 0.f;
            _Float16 cwh = (_Float16)cwv;
            half2_t cw2 = { cwh, cwh };
            int zc = min(max(zi, 0), 31), yc = min(max(yi, 0), 31), xc = min(max(xi, 0), 31);
            int cidx = (zc * 32 + yc) * 32 + xc;
            const h8v* pv = (const h8v*)(abase + (size_t)cidx * CCH);
            h8v q0 = pv[0], q1 = pv[1];
            val2[0] += cw2 * q0.a;  val2[1] += cw2 * q0.b;
            val2[2] += cw2 * q0.c;  val2[3] += cw2 * q0.d;
            val2[4] += cw2 * q1.a;  val2[5] += cw2 * q1.b;
            val2[6] += cw2 * q1.c;  val2[7] += cw2 * q1.d;
        }
        #pragma unroll
        for (int cpl = 0; cpl < 8; cpl++) {
            half2_t v2 = val2[cpl];
            const half2_t* wr = wt + ((size_t)k * 24 + gc * 8 + cpl) * CCH;  // uniform
            #pragma unroll
            for (int o = 0; o < CCH; o++) acc[o] = dot2f(v2, wr[o], acc[o]);
        }
    }
    float* op = out + (size_t)b * CCH * SVOL + s;
    #pragma unroll
    for (int o = 0; o < CCH; o++) atomicAdd(&op[(size_t)o * SVOL], acc[o]);
}

// ---- gate1: a2 = (c1 . dc + cb) * u; writes half2-pair a2p ----
__global__ __launch_bounds__(256, 4)
void gate1_kernel(const float* __restrict__ dc, const float* __restrict__ u,
                  const float* __restrict__ wt, const float* __restrict__ cb,
                  half2_t* __restrict__ a2p) {
    int tid = threadIdx.x;
    int g = blockIdx.y, b = blockIdx.z;
    int s = blockIdx.x * 256 + tid;
    size_t base = (size_t)b * CCH * SVOL + s;
    float acc[12];
    #pragma unroll
    for (int o = 0; o < 12; o++) acc[o] = cb[g * 12 + o];
    for (int ci = 0; ci < CCH; ci++) {
        float v = dc[base + (size_t)ci * SVOL];
        const float* wr = wt + ci * CCH + g * 12;
        #pragma unroll
        for (int o = 0; o < 12; o++) acc[o] += wr[o] * v;
    }
    #pragma unroll
    for (int o = 0; o < 12; o++) acc[o] *= u[base + (size_t)(g * 12 + o) * SVOL];
    half2_t* ap = a2p + ((size_t)b * 24 + g * 6) * SVOL + s;
    #pragma unroll
    for (int j = 0; j < 6; j++)
        ap[(size_t)j * SVOL] = half2_t{ (_Float16)acc[2 * j], (_Float16)acc[2 * j + 1] };
}

// ---- gate2: skip = x + gamma*(p2 . a2 + p2b + xn), fp16 dot2; writes fp32 skip + half2 skp ----
__global__ __launch_bounds__(256, 4)
void gate2_kernel(const half2_t* __restrict__ a2p, const float* __restrict__ xn,
                  const float* __restrict__ x,
                  const half2_t* __restrict__ wt, const float* __restrict__ p2b,
                  const float* __restrict__ gamma, float* __restrict__ skip,
                  half2_t* __restrict__ skp) {
    int tid = threadIdx.x;
    int g = blockIdx.y, b = blockIdx.z;
    int s = blockIdx.x * 256 + tid;
    size_t base = (size_t)b * CCH * SVOL + s;
    const half2_t* ab = a2p + (size_t)b * 24 * SVOL + s;
    float acc[12];
    #pragma unroll
    for (int o = 0; o < 12; o++) acc[o] = p2b[g * 12 + o];
    for (int cp = 0; cp < 24; cp++) {
        half2_t v2 = ab[(size_t)cp * SVOL];
        const half2_t* wr = wt + cp * CCH + g * 12;
        #pragma unroll
        for (int o = 0; o < 12; o++) acc[o] = dot2f(v2, wr[o], acc[o]);
    }
    float sv[12];
    #pragma unroll
    for (int o = 0; o < 12; o++) {
        int oc = g * 12 + o;
        float vv = acc[o] + xn[base + (size_t)oc * SVOL];
        sv[o] = x[base + (size_t)oc * SVOL] + gamma[oc] * vv;
        skip[base + (size_t)oc * SVOL] = sv[o];
    }
    half2_t* sp = skp + ((size_t)b * 24 + g * 6) * SVOL + s;
    #pragma unroll
    for (int j = 0; j < 6; j++)
        sp[(size_t)j * SVOL] = half2_t{ (_Float16)sv[2 * j], (_Float16)sv[2 * j + 1] };
}

// ---- u1: 3x3x3 conv + BN1 + LeakyReLU, fp16 dot2; writes packed half2 output ----
__global__ __launch_bounds__(256, 4)
void u1_kernel(const half2_t* __restrict__ skp, const half2_t* __restrict__ wt,
               const float* __restrict__ bs, const float* __restrict__ bb,
               const float* __restrict__ bm, const float* __restrict__ bv,
               half2_t* __restrict__ h1p) {
    int tid = threadIdx.x;
    int g = blockIdx.y, b = blockIdx.z;
    int s = blockIdx.x * 256 + tid;
    int z = s >> 10, y = (s >> 5) & 31, xx = s & 31;
    const half2_t* ib = skp + (size_t)b * 24 * SVOL;
    float acc[12];
    #pragma unroll
    for (int o = 0; o < 12; o++) acc[o] = 0.f;
    for (int tap = 0; tap < 27; tap++) {
        int dz = tap / 9 - 1, dy = (tap / 3) % 3 - 1, dx = tap % 3 - 1;
        int zz = z + dz, yy = y + dy, xv = xx + dx;
        bool ok = (zz >= 0 && zz < 32 && yy >= 0 && yy < 32 && xv >= 0 && xv < 32);
        if (ok) {
            int si = (zz * 32 + yy) * 32 + xv;
            for (int cp = 0; cp < 24; cp++) {
                half2_t v2 = ib[(size_t)cp * SVOL + si];
                const half2_t* wr = wt + ((size_t)tap * 24 + cp) * CCH + g * 12;  // uniform
                #pragma unroll
                for (int o = 0; o < 12; o++) acc[o] = dot2f(v2, wr[o], acc[o]);
            }
        }
    }
    float hv[12];
    #pragma unroll
    for (int o = 0; o < 12; o++) {
        int oc = g * 12 + o;
        float inv = rsqrtf(bv[oc] + 1e-5f);
        float h = (acc[o] - bm[oc]) * (bs[oc] * inv) + bb[oc];
        hv[o] = h >= 0.f ? h : 0.01f * h;
    }
    half2_t* op = h1p + ((size_t)b * 24 + g * 6) * SVOL + s;
    #pragma unroll
    for (int j = 0; j < 6; j++)
        op[(size_t)j * SVOL] = half2_t{ (_Float16)hv[2 * j], (_Float16)hv[2 * j + 1] };
}

// ---- u2_bn: 3x3x3 conv (fp16 dot2) + BN2 + (+skip fp32) + LeakyReLU -> attnp half2 ----
__global__ __launch_bounds__(256, 4)
void u2_bn_kernel(const half2_t* __restrict__ h1p, const float* __restrict__ skip,
                  const half2_t* __restrict__ wt,
                  const float* __restrict__ bs, const float* __restrict__ bb,
                  const float* __restrict__ bm, const float* __restrict__ bv,
                  half2_t* __restrict__ attnp) {
    int tid = threadIdx.x;
    int g = blockIdx.y, b = blockIdx.z;
    int s = blockIdx.x * 256 + tid;
    int z = s >> 10, y = (s >> 5) & 31, xx = s & 31;
    const half2_t* ib = h1p + (size_t)b * 24 * SVOL;
    float acc[12];
    #pragma unroll
    for (int o = 0; o < 12; o++) acc[o] = 0.f;
    for (int tap = 0; tap < 27; tap++) {
        int dz = tap / 9 - 1, dy = (tap / 3) % 3 - 1, dx = tap % 3 - 1;
        int zz = z + dz, yy = y + dy, xv = xx + dx;
        bool ok = (zz >= 0 && zz < 32 && yy >= 0 && yy < 32 && xv >= 0 && xv < 32);
        if (ok) {
            int si = (zz * 32 + yy) * 32 + xv;
            for (int cp = 0; cp < 24; cp++) {
                half2_t v2 = ib[(size_t)cp * SVOL + si];
                const half2_t* wr = wt + ((size_t)tap * 24 + cp) * CCH + g * 12;  // uniform
                #pragma unroll
                for (int o = 0; o < 12; o++) acc[o] = dot2f(v2, wr[o], acc[o]);
            }
        }
    }
    size_t base = (size_t)b * CCH * SVOL + s;
    float av[12];
    #pragma unroll
    for (int o = 0; o < 12; o++) {
        int oc = g * 12 + o;
        float inv = rsqrtf(bv[oc] + 1e-5f);
        float h = (acc[o] - bm[oc]) * (bs[oc] * inv) + bb[oc];
        float a = h + skip[base + (size_t)oc * SVOL];
        av[o] = a >= 0.f ? a : 0.01f * a;
    }
    half2_t* op = attnp + ((size_t)b * 24 + g * 6) * SVOL + s;
    #pragma unroll
    for (int j = 0; j < 6; j++)
        op[(size_t)j * SVOL] = half2_t{ (_Float16)av[2 * j], (_Float16)av[2 * j + 1] };
}

// ---- pr_final: out = skip + pr(attn), fp16 dot2 ----
__global__ __launch_bounds__(256, 4)
void pr_final_kernel(const half2_t* __restrict__ attnp, const float* __restrict__ skip,
                     const half2_t* __restrict__ wt, const float* __restrict__ prb,
                     float* __restrict__ out) {
    int tid = threadIdx.x;
    int g = blockIdx.y, b = blockIdx.z;
    int s = blockIdx.x * 256 + tid;
    size_t base = (size_t)b * CCH * SVOL + s;
    const half2_t* ab = attnp + (size_t)b * 24 * SVOL + s;
    float acc[12];
    #pragma unroll
    for (int o = 0; o < 12; o++) acc[o] = prb[g * 12 + o];
    for (int cp = 0; cp < 24; cp++) {
        half2_t v2 = ab[(size_t)cp * SVOL];
        const half2_t* wr = wt + cp * CCH + g * 12;
        #pragma unroll
        for (int o = 0; o < 12; o++) acc[o] = dot2f(v2, wr[o], acc[o]);
    }
    #pragma unroll
    for (int o = 0; o < 12; o++) {
        int oc = g * 12 + o;
        out[base + (size_t)oc * SVOL] = skip[base + (size_t)oc * SVOL] + acc[o];
    }
}

extern "C" void kernel_launch(void* const* d_in, const int* in_sizes, int n_in,
                              void* d_out, int out_size, void* d_ws, size_t ws_size,
                              hipStream_t stream) {
    (void)in_sizes; (void)n_in; (void)out_size; (void)ws_size;
    const float* x     = (const float*)d_in[0];
    const float* ln_s  = (const float*)d_in[1];
    const float* ln_b  = (const float*)d_in[2];
    const float* gamma = (const float*)d_in[3];
    const float* p1_w  = (const float*)d_in[4];
    const float* p1_b  = (const float*)d_in[5];
    const float* p2_w  = (const float*)d_in[6];
    const float* p2_b  = (const float*)d_in[7];
    const float* c0_w  = (const float*)d_in[8];
    const float* c0_b  = (const float*)d_in[9];
    const float* cs_w  = (const float*)d_in[10];
    const float* cs_b  = (const float*)d_in[11];
    const float* off_w = (const float*)d_in[12];
    const float* off_b = (const float*)d_in[13];
    const float* dc_w  = (const float*)d_in[14];
    const float* dc_b  = (const float*)d_in[15];
    const float* c1_w  = (const float*)d_in[16];
    const float* c1_b  = (const float*)d_in[17];
    const float* u1_w  = (const float*)d_in[18];
    const float* bn1_s = (const float*)d_in[19];
    const float* bn1_b = (const float*)d_in[20];
    const float* bn1_m = (const float*)d_in[21];
    const float* bn1_v = (const float*)d_in[22];
    const float* u2_w  = (const float*)d_in[23];
    const float* bn2_s = (const float*)d_in[24];
    const float* bn2_b = (const float*)d_in[25];
    const float* bn2_m = (const float*)d_in[26];
    const float* bn2_v = (const float*)d_in[27];
    const float* pr_w  = (const float*)d_in[28];
    const float* pr_b  = (const float*)d_in[29];
    float* out = (float*)d_out;

    float* wsf = (float*)d_ws;
    const size_t TS = (size_t)NB * CCH * SVOL;   // 3,145,728 floats
    float* xn   = out;            // d_out doubles as xn fp32 (dead after gate2)
    float* ubuf = wsf;            // u (gelu out fp32) -> [skp | h1p] (half2)
    float* bufA = wsf + TS;       // dw5 out -> [a1h | a1p] -> skip (fp32)
    float* bufB = wsf + 2 * TS;   // xnp (half2) -> dw7 out (a1) -> deform partials (dc)
    float* offb = wsf + 3 * TS;   // offset partials [B,81,S] -> a2p (half2) -> attnp (half2)
    float* wtb    = wsf + 3 * TS + (size_t)NB * 81 * SVOL;
    float* wt_offf = wtb;
    float* wt_dcf  = wt_offf + 104976;
    float* wt_u1f  = wt_dcf + 62208;
    float* wt_u2f  = wt_u1f + 62208;
    float* pt_p1  = wt_u2f + 62208;
    float* pt_c1  = pt_p1 + 2304;
    float* pt_p2  = pt_c1 + 2304;
    float* pt_pr  = pt_p2 + 2304;
    float* cb_all = pt_pr + 2304;

    __half*  a1h = (__half*)bufA;
    half2_t* a1p = (half2_t*)(bufA + TS / 2);
    half2_t* skp = (half2_t*)ubuf;
    half2_t* h1p = (half2_t*)(ubuf + TS / 2);
    half2_t* xnp = (half2_t*)bufB;
    half2_t* a2p = (half2_t*)offb;
    half2_t* attnp = (half2_t*)offb;
    half2_t* wt_offh = (half2_t*)wt_offf;
    half2_t* wt_dch  = (half2_t*)wt_dcf;
    half2_t* wt_u1h  = (half2_t*)wt_u1f;
    half2_t* wt_u2h  = (half2_t*)wt_u2f;
    half2_t* wt_p1h  = (half2_t*)pt_p1;
    half2_t* wt_p2h  = (half2_t*)pt_p2;
    half2_t* wt_prh  = (half2_t*)pt_pr;

    dim3 blk(256);
    dim3 gpos(SVOL / 256, NB);
    dim3 g4(SVOL / 256, 4, NB);
    dim3 g6(SVOL / 256, 6, NB);        // offconv: pair-split 2 x out-split 3
    dim3 g3d(SVOL / 256, 3, NB);
    dim3 gdwc(8, CCH, NB);
    dim3 gtr(SVOL / 64, NB);

    hipLaunchKernelGGL(reshape_pair_kernel, dim3((27 * 24 * 81 + 255) / 256), blk, 0, stream, off_w, wt_offh, 81);
    hipLaunchKernelGGL(reshape_pair_kernel, dim3((27 * 24 * 48 + 255) / 256), blk, 0, stream, dc_w,  wt_dch,  48);
    hipLaunchKernelGGL(reshape_pair_kernel, dim3((27 * 24 * 48 + 255) / 256), blk, 0, stream, u1_w,  wt_u1h,  48);
    hipLaunchKernelGGL(reshape_pair_kernel, dim3((27 * 24 * 48 + 255) / 256), blk, 0, stream, u2_w,  wt_u2h,  48);
    hipLaunchKernelGGL(t1x1_pair_kernel, dim3(5), blk, 0, stream, p1_w, wt_p1h);
    hipLaunchKernelGGL(t1x1_pair_kernel, dim3(5), blk, 0, stream, p2_w, wt_p2h);
    hipLaunchKernelGGL(t1x1_pair_kernel, dim3(5), blk, 0, stream, pr_w, wt_prh);
    hipLaunchKernelGGL(t1x1_kernel, dim3(9), blk, 0, stream, c1_w, pt_c1);
    hipLaunchKernelGGL(cb_kernel, dim3(1), dim3(64), 0, stream, c1_w, c1_b, dc_b, cb_all);

    hipLaunchKernelGGL(ln_kernel,            gpos, blk, 0, stream, x, ln_s, ln_b, xn, xnp);
    hipLaunchKernelGGL(p1_gelu_kernel,       g4,   blk, 0, stream, xnp, wt_p1h, p1_b, ubuf);
    hipLaunchKernelGGL(dw5_kernel,           gdwc, blk, 0, stream, ubuf, c0_w, c0_b, bufA);
    hipLaunchKernelGGL(dw7_kernel,           gdwc, blk, 0, stream, bufA, cs_w, cs_b, bufB);
    hipLaunchKernelGGL(transpose_pack_kernel, gtr, blk, 0, stream, bufB, a1h, a1p);
    hipMemsetAsync(offb, 0, (size_t)NB * 81 * SVOL * sizeof(float), stream);
    hipLaunchKernelGGL(offconv_kernel,       g6,   blk, 0, stream, a1p, wt_offh, offb);
    hipMemsetAsync(bufB, 0, TS * sizeof(float), stream);
    hipLaunchKernelGGL(deform_kernel,        g3d,  blk, 0, stream, a1h, offb, off_b, wt_dch, bufB);
    hipLaunchKernelGGL(gate1_kernel,         g4,   blk, 0, stream, bufB, ubuf, pt_c1, cb_all, a2p);
    hipLaunchKernelGGL(gate2_kernel,         g4,   blk, 0, stream, a2p, xn, x, wt_p2h, p2_b, gamma,
                       bufA, skp);
    hipLaunchKernelGGL(u1_kernel,            g4,   blk, 0, stream, skp, wt_u1h,
                       bn1_s, bn1_b, bn1_m, bn1_v, h1p);
    hipLaunchKernelGGL(u2_bn_kernel,         g4,   blk, 0, stream, h1p, bufA, wt_u2h,
                       bn2_s, bn2_b, bn2_m, bn2_v, attnp);
    hipLaunchKernelGGL(pr_final_kernel,      g4,   blk, 0, stream, attnp, bufA, wt_prh, pr_b, out);
}

// Round 22
// 610.199 us; speedup vs baseline: 1.2728x; 1.0861x over previous
//
#include <hip/hip_runtime.h>
#include <hip/hip_fp16.h>
#include <math.h>

#define CCH 48
#define SDIM 32
#define SVOL (SDIM*SDIM*SDIM)
#define NB 2

typedef _Float16 half2_t __attribute__((ext_vector_type(2)));
typedef _Float16 half4_t __attribute__((ext_vector_type(4)));
typedef float float4_t __attribute__((ext_vector_type(4)));

static __device__ __forceinline__ float dot2f(half2_t a, half2_t b, float c) {
#if __has_builtin(__builtin_amdgcn_fdot2)
    return __builtin_amdgcn_fdot2(a, b, c, false);
#else
    return c + (float)a[0] * (float)b[0] + (float)a[1] * (float)b[1];
#endif
}

// ======== one-off weight reshape kernels ========

__global__ __launch_bounds__(256)
void reshape_pair_kernel(const float* __restrict__ w, half2_t* __restrict__ wt, int NO) {
    int i = blockIdx.x * 256 + threadIdx.x;
    int total = 27 * 24 * NO;
    if (i < total) {
        int o = i % NO; int rem = i / NO; int cp = rem % 24; int k = rem / 24;
        float w0 = w[((size_t)o * CCH + 2 * cp) * 27 + k];
        float w1 = w[((size_t)o * CCH + 2 * cp + 1) * 27 + k];
        wt[i] = half2_t{ (_Float16)w0, (_Float16)w1 };
    }
}

// off_w[81][48][27] -> MFMA A-fragments: entry e = (((tap*6+mt)*3+ks)*4+kq)*16+row
// holds half4 {W[mt*16+row][ks*16+kq*4+h], h=0..3}, zero-padded rows 81..95.
__global__ __launch_bounds__(256)
void reshape_mfma_off_kernel(const float* __restrict__ w, half4_t* __restrict__ wA) {
    int e = blockIdx.x * 256 + threadIdx.x;
    if (e < 31104) {
        int row = e & 15;
        int kq = (e >> 4) & 3;
        int ks = (e / 64) % 3;
        int mt = (e / 192) % 6;
        int tap = e / 1152;
        int o = mt * 16 + row;
        half4_t v;
        #pragma unroll
        for (int h = 0; h < 4; h++) {
            int ci = ks * 16 + kq * 4 + h;
            float val = (o < 81) ? w[((size_t)o * CCH + ci) * 27 + tap] : 0.f;
            v[h] = (_Float16)val;
        }
        wA[e] = v;
    }
}

__global__ __launch_bounds__(256)
void t1x1_pair_kernel(const float* __restrict__ w, half2_t* __restrict__ wt) {
    int i = blockIdx.x * 256 + threadIdx.x;
    if (i < 24 * CCH) {
        int o = i % CCH, cp = i / CCH;
        wt[i] = half2_t{ (_Float16)w[o * CCH + 2 * cp], (_Float16)w[o * CCH + 2 * cp + 1] };
    }
}

__global__ __launch_bounds__(256)
void t1x1_kernel(const float* __restrict__ w, float* __restrict__ wt) {
    int i = blockIdx.x * 256 + threadIdx.x;
    if (i < CCH * CCH) { int ci = i / CCH, o = i % CCH; wt[i] = w[o * CCH + ci]; }
}

__global__ __launch_bounds__(64)
void cb_kernel(const float* __restrict__ c1w, const float* __restrict__ c1b,
               const float* __restrict__ dcb, float* __restrict__ cb) {
    int o = threadIdx.x;
    if (o < CCH) {
        float v = c1b[o];
        for (int ci = 0; ci < CCH; ci++) v += c1w[o * CCH + ci] * dcb[ci];
        cb[o] = v;
    }
}

// ---------------- LayerNorm over C; writes fp32 xn AND half2-pair xnp ----------------
__global__ __launch_bounds__(256)
void ln_kernel(const float* __restrict__ x, const float* __restrict__ ln_s,
               const float* __restrict__ ln_b, float* __restrict__ xn,
               half2_t* __restrict__ xnp) {
    int s = blockIdx.x * 256 + threadIdx.x;
    int b = blockIdx.y;
    const float* xb = x + (size_t)b * CCH * SVOL + s;
    float v[CCH];
    float mu = 0.f;
    #pragma unroll
    for (int c = 0; c < CCH; c++) { v[c] = xb[c * SVOL]; mu += v[c]; }
    mu *= (1.0f / CCH);
    float var = 0.f;
    #pragma unroll
    for (int c = 0; c < CCH; c++) { float d = v[c] - mu; var += d * d; }
    var *= (1.0f / CCH);
    float inv = rsqrtf(var + 1e-5f);
    float* o = xn + (size_t)b * CCH * SVOL + s;
    float nv[CCH];
    #pragma unroll
    for (int c = 0; c < CCH; c++) { nv[c] = (v[c] - mu) * inv * ln_s[c] + ln_b[c]; o[c * SVOL] = nv[c]; }
    half2_t* xp = xnp + (size_t)b * 24 * SVOL + s;
    #pragma unroll
    for (int cp = 0; cp < 24; cp++)
        xp[(size_t)cp * SVOL] = half2_t{ (_Float16)nv[2 * cp], (_Float16)nv[2 * cp + 1] };
}

// ---------------- 1x1x1 conv + exact GELU (4 groups x 12), fp16 dot2 ----------------
__global__ __launch_bounds__(256, 4)
void p1_gelu_kernel(const half2_t* __restrict__ xnp, const half2_t* __restrict__ wt,
                    const float* __restrict__ bias, float* __restrict__ u) {
    int tid = threadIdx.x;
    int g = blockIdx.y, b = blockIdx.z;
    int s = blockIdx.x * 256 + tid;
    const half2_t* xb = xnp + (size_t)b * 24 * SVOL + s;
    float acc[12];
    #pragma unroll
    for (int o = 0; o < 12; o++) acc[o] = bias[g * 12 + o];
    for (int cp = 0; cp < 24; cp++) {
        half2_t v2 = xb[(size_t)cp * SVOL];
        const half2_t* wr = wt + cp * CCH + g * 12;
        #pragma unroll
        for (int o = 0; o < 12; o++) acc[o] = dot2f(v2, wr[o], acc[o]);
    }
    float* ub = u + (size_t)b * CCH * SVOL + s + (size_t)(g * 12) * SVOL;
    #pragma unroll
    for (int o = 0; o < 12; o++) {
        float a = acc[o];
        ub[o * SVOL] = 0.5f * a * (1.0f + erff(a * 0.70710678118654752f));
    }
}

// ---- depthwise 5x5x5 pad 2: half-column blocking (16 z/thread, window cache) ----
__global__ __launch_bounds__(256, 4)
void dw5_kernel(const float* __restrict__ in, const float* __restrict__ w,
                const float* __restrict__ bias, float* __restrict__ out) {
    int tid = threadIdx.x;
    int c = blockIdx.y, b = blockIdx.z;
    const float* wc = w + c * 125;
    int bx = blockIdx.x;
    int yx = (bx >> 1) * 256 + tid;
    int z0 = (bx & 1) * 16;
    int y = yx >> 5, xx = yx & 31;
    const float* ib = in + ((size_t)b * CCH + c) * SVOL;
    float acc[16];
    float bv = bias[c];
    #pragma unroll
    for (int z = 0; z < 16; z++) acc[z] = bv;
    for (int ty = 0; ty < 5; ty++) {
        int yy = y + ty - 2; if (yy < 0 || yy >= 32) continue;
        for (int tx = 0; tx < 5; tx++) {
            int xv = xx + tx - 2; if (xv < 0 || xv >= 32) continue;
            const float* col = ib + yy * 32 + xv;
            float cv[20];
            #pragma unroll
            for (int j = 0; j < 20; j++) {
                int zz = z0 - 2 + j;
                cv[j] = (zz >= 0 && zz < 32) ? col[(size_t)zz * 1024] : 0.f;
            }
            #pragma unroll
            for (int tz = 0; tz < 5; tz++) {
                float wv = wc[(tz * 5 + ty) * 5 + tx];
                #pragma unroll
                for (int z = 0; z < 16; z++) acc[z] += wv * cv[z + tz];
            }
        }
    }
    float* ob = out + ((size_t)b * CCH + c) * SVOL + y * 32 + xx;
    #pragma unroll
    for (int z = 0; z < 16; z++) ob[(size_t)(z0 + z) * 1024] = acc[z];
}

// ---- depthwise 7x7x7 dil 3 pad 9: half-column blocking (16 z/thread, window cache) ----
__global__ __launch_bounds__(256, 4)
void dw7_kernel(const float* __restrict__ in, const float* __restrict__ w,
                const float* __restrict__ bias, float* __restrict__ out) {
    int tid = threadIdx.x;
    int c = blockIdx.y, b = blockIdx.z;
    const float* wc = w + c * 343;
    int bx = blockIdx.x;
    int yx = (bx >> 1) * 256 + tid;
    int z0 = (bx & 1) * 16;
    int y = yx >> 5, xx = yx & 31;
    const float* ib = in + ((size_t)b * CCH + c) * SVOL;
    float acc[16];
    float bv = bias[c];
    #pragma unroll
    for (int z = 0; z < 16; z++) acc[z] = bv;
    for (int ty = 0; ty < 7; ty++) {
        int yy = y + 3 * (ty - 3); if (yy < 0 || yy >= 32) continue;
        for (int tx = 0; tx < 7; tx++) {
            int xv = xx + 3 * (tx - 3); if (xv < 0 || xv >= 32) continue;
            const float* col = ib + yy * 32 + xv;
            float cv[34];
            #pragma unroll
            for (int j = 0; j < 34; j++) {
                int zz = z0 - 9 + j;
                cv[j] = (zz >= 0 && zz < 32) ? col[(size_t)zz * 1024] : 0.f;
            }
            #pragma unroll
            for (int tz = 0; tz < 7; tz++) {
                float wv = wc[(tz * 7 + ty) * 7 + tx];
                #pragma unroll
                for (int z = 0; z < 16; z++) acc[z] += wv * cv[z + 3 * tz];
            }
        }
    }
    float* ob = out + ((size_t)b * CCH + c) * SVOL + y * 32 + xx;
    #pragma unroll
    for (int z = 0; z < 16; z++) ob[(size_t)(z0 + z) * 1024] = acc[z];
}

// ---- a1 fp32 [48][S] -> a1h fp16 [S][48] (deform + offconv operand) ----
__global__ __launch_bounds__(256)
void transpose_pack_kernel(const float* __restrict__ a1, __half* __restrict__ a1h) {
    __shared__ float tile[CCH * 65];
    int tid = threadIdx.x;
    int b = blockIdx.y;
    int s0 = blockIdx.x * 64;
    const float* ib = a1 + (size_t)b * CCH * SVOL + s0;
    for (int i = tid; i < CCH * 64; i += 256) {
        int c = i >> 6, p = i & 63;
        tile[c * 65 + p] = ib[(size_t)c * SVOL + p];
    }
    __syncthreads();
    __half* ob = a1h + ((size_t)b * SVOL + s0) * CCH;
    for (int i = tid; i < 64 * CCH; i += 256) {
        int p = i / CCH, c = i % CCH;
        ob[i] = __float2half(tile[c * 65 + p]);
    }
}

// ---- offset conv 3x3x3 via MFMA implicit-GEMM: 4x4x4 tile, halo in LDS, no atomics ----
__global__ __launch_bounds__(256, 4)
void offconv_mfma_kernel(const __half* __restrict__ a1h, const half4_t* __restrict__ wA,
                         float* __restrict__ off) {
    __shared__ __half halo[216 * 52];     // [6x6x6 pos][48 ch + 4 pad], 22.5 KB
    int tid = threadIdx.x;
    int t = blockIdx.x;                    // 0..511 spatial tile
    int b = blockIdx.y;
    int tz0 = (t >> 6) * 4, ty0 = ((t >> 3) & 7) * 4, tx0 = (t & 7) * 4;
    const __half* ab = a1h + (size_t)b * SVOL * CCH;
    for (int idx = tid; idx < 216 * 24; idx += 256) {
        int hpos = idx / 24, kp = idx % 24;
        int hz = hpos / 36, hy = (hpos / 6) % 6, hx = hpos % 6;
        int gz = tz0 + hz - 1, gy = ty0 + hy - 1, gx = tx0 + hx - 1;
        unsigned int v = 0u;
        if (gz >= 0 && gz < 32 && gy >= 0 && gy < 32 && gx >= 0 && gx < 32) {
            int s = (gz * 32 + gy) * 32 + gx;
            v = *reinterpret_cast<const unsigned int*>(ab + (size_t)s * CCH + kp * 2);
        }
        *reinterpret_cast<unsigned int*>(&halo[hpos * 52 + kp * 2]) = v;
    }
    __syncthreads();
    int wave = tid >> 6, lane = tid & 63;
    int col = lane & 15;                   // position col / A row
    int kq = lane >> 4;                    // k-quad 0..3
    int py = col >> 2, px = col & 3;
    int pz = wave;
    float4_t acc[6];
    #pragma unroll
    for (int m = 0; m < 6; m++) acc[m] = (float4_t)0.f;
    for (int tap = 0; tap < 27; tap++) {
        int dz = tap / 9, dy = (tap / 3) % 3, dx = tap % 3;
        int hbase = ((pz + dz) * 36 + (py + dy) * 6 + (px + dx)) * 52 + kq * 4;
        half4_t bf0 = *reinterpret_cast<const half4_t*>(&halo[hbase]);
        half4_t bf1 = *reinterpret_cast<const half4_t*>(&halo[hbase + 16]);
        half4_t bf2 = *reinterpret_cast<const half4_t*>(&halo[hbase + 32]);
        #pragma unroll
        for (int mt = 0; mt < 6; mt++) {
            int fb = (tap * 6 + mt) * 12 + kq;     // f index for ks=0
            half4_t a0 = wA[(size_t)fb * 16 + col];
            half4_t a1 = wA[(size_t)(fb + 4) * 16 + col];
            half4_t a2 = wA[(size_t)(fb + 8) * 16 + col];
            acc[mt] = __builtin_amdgcn_mfma_f32_16x16x16f16(a0, bf0, acc[mt], 0, 0, 0);
            acc[mt] = __builtin_amdgcn_mfma_f32_16x16x16f16(a1, bf1, acc[mt], 0, 0, 0);
            acc[mt] = __builtin_amdgcn_mfma_f32_16x16x16f16(a2, bf2, acc[mt], 0, 0, 0);
        }
    }
    int sg = ((tz0 + pz) * 32 + ty0 + py) * 32 + tx0 + px;
    float* ob = off + (size_t)b * 81 * SVOL + sg;
    #pragma unroll
    for (int mt = 0; mt < 6; mt++) {
        #pragma unroll
        for (int r = 0; r < 4; r++) {
            int orow = mt * 16 + kq * 4 + r;
            if (orow < 81) ob[(size_t)orow * SVOL] = acc[mt][r];
        }
    }
}

// ---- deformable conv 3x3x3: ci-split 3 (16 ch), packed fp16 interp + dot2 matmul ----
struct h8v { half2_t a, b, c, d; };   // 16 bytes = 8 halves

__global__ __launch_bounds__(256, 4)
void deform_kernel(const __half* __restrict__ a1h, const float* __restrict__ off,
                   const float* __restrict__ off_b,
                   const half2_t* __restrict__ wt, float* __restrict__ out) {
    int tid = threadIdx.x;
    int gc = blockIdx.y;            // ci group 0..2 (16 ch = 8 pairs each)
    int b = blockIdx.z;
    int s = blockIdx.x * 256 + tid;
    int z = s >> 10, y = (s >> 5) & 31, xx = s & 31;
    const __half* abase = a1h + (size_t)b * SVOL * CCH + gc * 16;
    const float* ob = off + (size_t)b * 81 * SVOL + s;
    float acc[CCH];
    #pragma unroll
    for (int o = 0; o < CCH; o++) acc[o] = 0.f;
    for (int k = 0; k < 27; k++) {
        int kd = k / 9 - 1, kh = (k / 3) % 3 - 1, kw = k % 3 - 1;
        float zf = (float)(z + kd) + ob[(size_t)(k * 3 + 0) * SVOL] + off_b[k * 3 + 0];
        float yf = (float)(y + kh) + ob[(size_t)(k * 3 + 1) * SVOL] + off_b[k * 3 + 1];
        float xf = (float)(xx + kw) + ob[(size_t)(k * 3 + 2) * SVOL] + off_b[k * 3 + 2];
        float z0 = floorf(zf), y0 = floorf(yf), x0 = floorf(xf);
        float tz = zf - z0, ty = yf - y0, tx = xf - x0;
        int iz0 = (int)z0, iy0 = (int)y0, ix0 = (int)x0;
        half2_t val2[8];
        #pragma unroll
        for (int j = 0; j < 8; j++) val2[j] = (half2_t)(_Float16)0;
        #pragma unroll
        for (int corner = 0; corner < 8; corner++) {
            int dz = corner >> 2, dy = (corner >> 1) & 1, dx = corner & 1;
            int zi = iz0 + dz, yi = iy0 + dy, xi = ix0 + dx;
            bool valid = (zi >= 0 && zi < 32 && yi >= 0 && yi < 32 && xi >= 0 && xi < 32);
            float wgt = (dz ? tz : 1.f - tz) * (dy ? ty : 1.f - ty) * (dx ? tx : 1.f - tx);
            float cwv = valid ? wgt : 0.f;
            _Float16 cwh = (_Float16)cwv;
            half2_t cw2 = { cwh, cwh };
            int zc = min(max(zi, 0), 31), yc = min(max(yi, 0), 31), xc = min(max(xi, 0), 31);
            int cidx = (zc * 32 + yc) * 32 + xc;
            const h8v* pv = (const h8v*)(abase + (size_t)cidx * CCH);
            h8v q0 = pv[0], q1 = pv[1];
            val2[0] += cw2 * q0.a;  val2[1] += cw2 * q0.b;
            val2[2] += cw2 * q0.c;  val2[3] += cw2 * q0.d;
            val2[4] += cw2 * q1.a;  val2[5] += cw2 * q1.b;
            val2[6] += cw2 * q1.c;  val2[7] += cw2 * q1.d;
        }
        #pragma unroll
        for (int cpl = 0; cpl < 8; cpl++) {
            half2_t v2 = val2[cpl];
            const half2_t* wr = wt + ((size_t)k * 24 + gc * 8 + cpl) * CCH;  // uniform
            #pragma unroll
            for (int o = 0; o < CCH; o++) acc[o] = dot2f(v2, wr[o], acc[o]);
        }
    }
    float* op = out + (size_t)b * CCH * SVOL + s;
    #pragma unroll
    for (int o = 0; o < CCH; o++) atomicAdd(&op[(size_t)o * SVOL], acc[o]);
}

// ---- gate1: a2 = (c1 . dc + cb) * u; writes half2-pair a2p ----
__global__ __launch_bounds__(256, 4)
void gate1_kernel(const float* __restrict__ dc, const float* __restrict__ u,
                  const float* __restrict__ wt, const float* __restrict__ cb,
                  half2_t* __restrict__ a2p) {
    int tid = threadIdx.x;
    int g = blockIdx.y, b = blockIdx.z;
    int s = blockIdx.x * 256 + tid;
    size_t base = (size_t)b * CCH * SVOL + s;
    float acc[12];
    #pragma unroll
    for (int o = 0; o < 12; o++) acc[o] = cb[g * 12 + o];
    for (int ci = 0; ci < CCH; ci++) {
        float v = dc[base + (size_t)ci * SVOL];
        const float* wr = wt + ci * CCH + g * 12;
        #pragma unroll
        for (int o = 0; o < 12; o++) acc[o] += wr[o] * v;
    }
    #pragma unroll
    for (int o = 0; o < 12; o++) acc[o] *= u[base + (size_t)(g * 12 + o) * SVOL];
    half2_t* ap = a2p + ((size_t)b * 24 + g * 6) * SVOL + s;
    #pragma unroll
    for (int j = 0; j < 6; j++)
        ap[(size_t)j * SVOL] = half2_t{ (_Float16)acc[2 * j], (_Float16)acc[2 * j + 1] };
}

// ---- gate2: skip = x + gamma*(p2 . a2 + p2b + xn), fp16 dot2; writes fp32 skip + half2 skp ----
__global__ __launch_bounds__(256, 4)
void gate2_kernel(const half2_t* __restrict__ a2p, const float* __restrict__ xn,
                  const float* __restrict__ x,
                  const half2_t* __restrict__ wt, const float* __restrict__ p2b,
                  const float* __restrict__ gamma, float* __restrict__ skip,
                  half2_t* __restrict__ skp) {
    int tid = threadIdx.x;
    int g = blockIdx.y, b = blockIdx.z;
    int s = blockIdx.x * 256 + tid;
    size_t base = (size_t)b * CCH * SVOL + s;
    const half2_t* ab = a2p + (size_t)b * 24 * SVOL + s;
    float acc[12];
    #pragma unroll
    for (int o = 0; o < 12; o++) acc[o] = p2b[g * 12 + o];
    for (int cp = 0; cp < 24; cp++) {
        half2_t v2 = ab[(size_t)cp * SVOL];
        const half2_t* wr = wt + cp * CCH + g * 12;
        #pragma unroll
        for (int o = 0; o < 12; o++) acc[o] = dot2f(v2, wr[o], acc[o]);
    }
    float sv[12];
    #pragma unroll
    for (int o = 0; o < 12; o++) {
        int oc = g * 12 + o;
        float vv = acc[o] + xn[base + (size_t)oc * SVOL];
        sv[o] = x[base + (size_t)oc * SVOL] + gamma[oc] * vv;
        skip[base + (size_t)oc * SVOL] = sv[o];
    }
    half2_t* sp = skp + ((size_t)b * 24 + g * 6) * SVOL + s;
    #pragma unroll
    for (int j = 0; j < 6; j++)
        sp[(size_t)j * SVOL] = half2_t{ (_Float16)sv[2 * j], (_Float16)sv[2 * j + 1] };
}

// ---- u1: 3x3x3 conv + BN1 + LeakyReLU, fp16 dot2; writes packed half2 output ----
__global__ __launch_bounds__(256, 4)
void u1_kernel(const half2_t* __restrict__ skp, const half2_t* __restrict__ wt,
               const float* __restrict__ bs, const float* __restrict__ bb,
               const float* __restrict__ bm, const float* __restrict__ bv,
               half2_t* __restrict__ h1p) {
    int tid = threadIdx.x;
    int g = blockIdx.y, b = blockIdx.z;
    int s = blockIdx.x * 256 + tid;
    int z = s >> 10, y = (s >> 5) & 31, xx = s & 31;
    const half2_t* ib = skp + (size_t)b * 24 * SVOL;
    float acc[12];
    #pragma unroll
    for (int o = 0; o < 12; o++) acc[o] = 0.f;
    for (int tap = 0; tap < 27; tap++) {
        int dz = tap / 9 - 1, dy = (tap / 3) % 3 - 1, dx = tap % 3 - 1;
        int zz = z + dz, yy = y + dy, xv = xx + dx;
        bool ok = (zz >= 0 && zz < 32 && yy >= 0 && yy < 32 && xv >= 0 && xv < 32);
        if (ok) {
            int si = (zz * 32 + yy) * 32 + xv;
            for (int cp = 0; cp < 24; cp++) {
                half2_t v2 = ib[(size_t)cp * SVOL + si];
                const half2_t* wr = wt + ((size_t)tap * 24 + cp) * CCH + g * 12;  // uniform
                #pragma unroll
                for (int o = 0; o < 12; o++) acc[o] = dot2f(v2, wr[o], acc[o]);
            }
        }
    }
    float hv[12];
    #pragma unroll
    for (int o = 0; o < 12; o++) {
        int oc = g * 12 + o;
        float inv = rsqrtf(bv[oc] + 1e-5f);
        float h = (acc[o] - bm[oc]) * (bs[oc] * inv) + bb[oc];
        hv[o] = h >= 0.f ? h : 0.01f * h;
    }
    half2_t* op = h1p + ((size_t)b * 24 + g * 6) * SVOL + s;
    #pragma unroll
    for (int j = 0; j < 6; j++)
        op[(size_t)j * SVOL] = half2_t{ (_Float16)hv[2 * j], (_Float16)hv[2 * j + 1] };
}

// ---- u2_bn: 3x3x3 conv (fp16 dot2) + BN2 + (+skip fp32) + LeakyReLU -> attnp half2 ----
__global__ __launch_bounds__(256, 4)
void u2_bn_kernel(const half2_t* __restrict__ h1p, const float* __restrict__ skip,
                  const half2_t* __restrict__ wt,
                  const float* __restrict__ bs, const float* __restrict__ bb,
                  const float* __restrict__ bm, const float* __restrict__ bv,
                  half2_t* __restrict__ attnp) {
    int tid = threadIdx.x;
    int g = blockIdx.y, b = blockIdx.z;
    int s = blockIdx.x * 256 + tid;
    int z = s >> 10, y = (s >> 5) & 31, xx = s & 31;
    const half2_t* ib = h1p + (size_t)b * 24 * SVOL;
    float acc[12];
    #pragma unroll
    for (int o = 0; o < 12; o++) acc[o] = 0.f;
    for (int tap = 0; tap < 27; tap++) {
        int dz = tap / 9 - 1, dy = (tap / 3) % 3 - 1, dx = tap % 3 - 1;
        int zz = z + dz, yy = y + dy, xv = xx + dx;
        bool ok = (zz >= 0 && zz < 32 && yy >= 0 && yy < 32 && xv >= 0 && xv < 32);
        if (ok) {
            int si = (zz * 32 + yy) * 32 + xv;
            for (int cp = 0; cp < 24; cp++) {
                half2_t v2 = ib[(size_t)cp * SVOL + si];
                const half2_t* wr = wt + ((size_t)tap * 24 + cp) * CCH + g * 12;  // uniform
                #pragma unroll
                for (int o = 0; o < 12; o++) acc[o] = dot2f(v2, wr[o], acc[o]);
            }
        }
    }
    size_t base = (size_t)b * CCH * SVOL + s;
    float av[12];
    #pragma unroll
    for (int o = 0; o < 12; o++) {
        int oc = g * 12 + o;
        float inv = rsqrtf(bv[oc] + 1e-5f);
        float h = (acc[o] - bm[oc]) * (bs[oc] * inv) + bb[oc];
        float a = h + skip[base + (size_t)oc * SVOL];
        av[o] = a >= 0.f ? a : 0.01f * a;
    }
    half2_t* op = attnp + ((size_t)b * 24 + g * 6) * SVOL + s;
    #pragma unroll
    for (int j = 0; j < 6; j++)
        op[(size_t)j * SVOL] = half2_t{ (_Float16)av[2 * j], (_Float16)av[2 * j + 1] };
}

// ---- pr_final: out = skip + pr(attn), fp16 dot2 ----
__global__ __launch_bounds__(256, 4)
void pr_final_kernel(const half2_t* __restrict__ attnp, const float* __restrict__ skip,
                     const half2_t* __restrict__ wt, const float* __restrict__ prb,
                     float* __restrict__ out) {
    int tid = threadIdx.x;
    int g = blockIdx.y, b = blockIdx.z;
    int s = blockIdx.x * 256 + tid;
    size_t base = (size_t)b * CCH * SVOL + s;
    const half2_t* ab = attnp + (size_t)b * 24 * SVOL + s;
    float acc[12];
    #pragma unroll
    for (int o = 0; o < 12; o++) acc[o] = prb[g * 12 + o];
    for (int cp = 0; cp < 24; cp++) {
        half2_t v2 = ab[(size_t)cp * SVOL];
        const half2_t* wr = wt + cp * CCH + g * 12;
        #pragma unroll
        for (int o = 0; o < 12; o++) acc[o] = dot2f(v2, wr[o], acc[o]);
    }
    #pragma unroll
    for (int o = 0; o < 12; o++) {
        int oc = g * 12 + o;
        out[base + (size_t)oc * SVOL] = skip[base + (size_t)oc * SVOL] + acc[o];
    }
}

extern "C" void kernel_launch(void* const* d_in, const int* in_sizes, int n_in,
                              void* d_out, int out_size, void* d_ws, size_t ws_size,
                              hipStream_t stream) {
    (void)in_sizes; (void)n_in; (void)out_size; (void)ws_size;
    const float* x     = (const float*)d_in[0];
    const float* ln_s  = (const float*)d_in[1];
    const float* ln_b  = (const float*)d_in[2];
    const float* gamma = (const float*)d_in[3];
    const float* p1_w  = (const float*)d_in[4];
    const float* p1_b  = (const float*)d_in[5];
    const float* p2_w  = (const float*)d_in[6];
    const float* p2_b  = (const float*)d_in[7];
    const float* c0_w  = (const float*)d_in[8];
    const float* c0_b  = (const float*)d_in[9];
    const float* cs_w  = (const float*)d_in[10];
    const float* cs_b  = (const float*)d_in[11];
    const float* off_w = (const float*)d_in[12];
    const float* off_b = (const float*)d_in[13];
    const float* dc_w  = (const float*)d_in[14];
    const float* dc_b  = (const float*)d_in[15];
    const float* c1_w  = (const float*)d_in[16];
    const float* c1_b  = (const float*)d_in[17];
    const float* u1_w  = (const float*)d_in[18];
    const float* bn1_s = (const float*)d_in[19];
    const float* bn1_b = (const float*)d_in[20];
    const float* bn1_m = (const float*)d_in[21];
    const float* bn1_v = (const float*)d_in[22];
    const float* u2_w  = (const float*)d_in[23];
    const float* bn2_s = (const float*)d_in[24];
    const float* bn2_b = (const float*)d_in[25];
    const float* bn2_m = (const float*)d_in[26];
    const float* bn2_v = (const float*)d_in[27];
    const float* pr_w  = (const float*)d_in[28];
    const float* pr_b  = (const float*)d_in[29];
    float* out = (float*)d_out;

    float* wsf = (float*)d_ws;
    const size_t TS = (size_t)NB * CCH * SVOL;   // 3,145,728 floats
    float* xn   = out;            // d_out doubles as xn fp32 (dead after gate2)
    float* ubuf = wsf;            // u (gelu out fp32) -> [skp | h1p] (half2)
    float* bufA = wsf + TS;       // dw5 out -> a1h -> skip (fp32)
    float* bufB = wsf + 2 * TS;   // xnp (half2) -> dw7 out (a1) -> deform partials (dc)
    float* offb = wsf + 3 * TS;   // offsets [B,81,S] -> a2p (half2) -> attnp (half2)
    float* wtb    = wsf + 3 * TS + (size_t)NB * 81 * SVOL;
    float* wt_offf = wtb;                   // MFMA A frags: 31104 half4 = 62208 floats
    float* wt_dcf  = wt_offf + 104976;
    float* wt_u1f  = wt_dcf + 62208;
    float* wt_u2f  = wt_u1f + 62208;
    float* pt_p1  = wt_u2f + 62208;
    float* pt_c1  = pt_p1 + 2304;
    float* pt_p2  = pt_c1 + 2304;
    float* pt_pr  = pt_p2 + 2304;
    float* cb_all = pt_pr + 2304;

    __half*  a1h = (__half*)bufA;
    half2_t* skp = (half2_t*)ubuf;
    half2_t* h1p = (half2_t*)(ubuf + TS / 2);
    half2_t* xnp = (half2_t*)bufB;
    half2_t* a2p = (half2_t*)offb;
    half2_t* attnp = (half2_t*)offb;
    half4_t* wA_off = (half4_t*)wt_offf;
    half2_t* wt_dch  = (half2_t*)wt_dcf;
    half2_t* wt_u1h  = (half2_t*)wt_u1f;
    half2_t* wt_u2h  = (half2_t*)wt_u2f;
    half2_t* wt_p1h  = (half2_t*)pt_p1;
    half2_t* wt_p2h  = (half2_t*)pt_p2;
    half2_t* wt_prh  = (half2_t*)pt_pr;

    dim3 blk(256);
    dim3 gpos(SVOL / 256, NB);
    dim3 g4(SVOL / 256, 4, NB);
    dim3 gmf(512, NB);                 // offconv MFMA: 8x8x8 spatial tiles
    dim3 g3d(SVOL / 256, 3, NB);
    dim3 gdwc(8, CCH, NB);
    dim3 gtr(SVOL / 64, NB);

    hipLaunchKernelGGL(reshape_mfma_off_kernel, dim3((31104 + 255) / 256), blk, 0, stream, off_w, wA_off);
    hipLaunchKernelGGL(reshape_pair_kernel, dim3((27 * 24 * 48 + 255) / 256), blk, 0, stream, dc_w,  wt_dch,  48);
    hipLaunchKernelGGL(reshape_pair_kernel, dim3((27 * 24 * 48 + 255) / 256), blk, 0, stream, u1_w,  wt_u1h,  48);
    hipLaunchKernelGGL(reshape_pair_kernel, dim3((27 * 24 * 48 + 255) / 256), blk, 0, stream, u2_w,  wt_u2h,  48);
    hipLaunchKernelGGL(t1x1_pair_kernel, dim3(5), blk, 0, stream, p1_w, wt_p1h);
    hipLaunchKernelGGL(t1x1_pair_kernel, dim3(5), blk, 0, stream, p2_w, wt_p2h);
    hipLaunchKernelGGL(t1x1_pair_kernel, dim3(5), blk, 0, stream, pr_w, wt_prh);
    hipLaunchKernelGGL(t1x1_kernel, dim3(9), blk, 0, stream, c1_w, pt_c1);
    hipLaunchKernelGGL(cb_kernel, dim3(1), dim3(64), 0, stream, c1_w, c1_b, dc_b, cb_all);

    hipLaunchKernelGGL(ln_kernel,            gpos, blk, 0, stream, x, ln_s, ln_b, xn, xnp);
    hipLaunchKernelGGL(p1_gelu_kernel,       g4,   blk, 0, stream, xnp, wt_p1h, p1_b, ubuf);
    hipLaunchKernelGGL(dw5_kernel,           gdwc, blk, 0, stream, ubuf, c0_w, c0_b, bufA);
    hipLaunchKernelGGL(dw7_kernel,           gdwc, blk, 0, stream, bufA, cs_w, cs_b, bufB);
    hipLaunchKernelGGL(transpose_pack_kernel, gtr, blk, 0, stream, bufB, a1h);
    hipLaunchKernelGGL(offconv_mfma_kernel,  gmf,  blk, 0, stream, a1h, wA_off, offb);
    hipMemsetAsync(bufB, 0, TS * sizeof(float), stream);
    hipLaunchKernelGGL(deform_kernel,        g3d,  blk, 0, stream, a1h, offb, off_b, wt_dch, bufB);
    hipLaunchKernelGGL(gate1_kernel,         g4,   blk, 0, stream, bufB, ubuf, pt_c1, cb_all, a2p);
    hipLaunchKernelGGL(gate2_kernel,         g4,   blk, 0, stream, a2p, xn, x, wt_p2h, p2_b, gamma,
                       bufA, skp);
    hipLaunchKernelGGL(u1_kernel,            g4,   blk, 0, stream, skp, wt_u1h,
                       bn1_s, bn1_b, bn1_m, bn1_v, h1p);
    hipLaunchKernelGGL(u2_bn_kernel,         g4,   blk, 0, stream, h1p, bufA, wt_u2h,
                       bn2_s, bn2_b, bn2_m, bn2_v, attnp);
    hipLaunchKernelGGL(pr_final_kernel,      g4,   blk, 0, stream, attnp, bufA, wt_prh, pr_b, out);
}